// Round 2
// baseline (1685.025 us; speedup 1.0000x reference)
//
#include <hip/hip_runtime.h>
#include <math.h>

// ---------------- problem constants ----------------
#define BB   16
#define LL   1024
#define BLR  (BB*LL)        // 16384 rows
#define DM   256
#define DS   16
#define FD   115
#define NF   4
#define NACTN 19
#define GH   32
#define GKN  6
#define AEM  16
#define NP   22
#define CATD 304            // DM + GH + AEM
#define KKAN 240            // 230 padded to x16
#define KREAL 230           // 115 inputs x {ln_x, sum_basis}

// NOTE on the KAN: the reference einsum 'big,oid->bo' has MISMATCHED grid
// subscripts (g vs d), so it computes (sum_g basis) * (sum_d Wsp) contracted
// over i only. Effective per-input features: [x_ln, sum_g exp(-(x_ln-g)^2 b)]
// against weights [kan_scale[o,i], sum_d kan_spline[o,i,d]].

// ---------------- generic f32 GEMM: C[M,N] = act(A[M,K] @ W[N,K]^T + bias) (+C) ----
// 64x64 tile, 256 threads, 4x4 microtile, K step 16. M%64==0, K%16==0. N arbitrary.
__global__ __launch_bounds__(256) void gemm_f32(
    const float* __restrict__ A, const float* __restrict__ W,
    const float* __restrict__ bias, float* __restrict__ C,
    int N, int K, int act, int accum)
{
    __shared__ float As[16][68];
    __shared__ float Ws[16][68];
    const int tid = threadIdx.x;
    const int bm = blockIdx.x * 64;
    const int bn = blockIdx.y * 64;
    const int ty = tid >> 4, tx = tid & 15;
    const int lr = tid >> 2;            // 0..63 tile row
    const int lk = (tid & 3) * 4;       // 0,4,8,12
    float acc[4][4] = {{0.f,0.f,0.f,0.f},{0.f,0.f,0.f,0.f},{0.f,0.f,0.f,0.f},{0.f,0.f,0.f,0.f}};

    for (int k0 = 0; k0 < K; k0 += 16) {
        float4 av = *reinterpret_cast<const float4*>(A + (size_t)(bm + lr) * K + k0 + lk);
        As[lk+0][lr] = av.x; As[lk+1][lr] = av.y; As[lk+2][lr] = av.z; As[lk+3][lr] = av.w;
        float4 wv = make_float4(0.f, 0.f, 0.f, 0.f);
        if (bn + lr < N)
            wv = *reinterpret_cast<const float4*>(W + (size_t)(bn + lr) * K + k0 + lk);
        Ws[lk+0][lr] = wv.x; Ws[lk+1][lr] = wv.y; Ws[lk+2][lr] = wv.z; Ws[lk+3][lr] = wv.w;
        __syncthreads();
        #pragma unroll
        for (int kk = 0; kk < 16; ++kk) {
            float4 a4 = *reinterpret_cast<const float4*>(&As[kk][ty*4]);
            float4 b4 = *reinterpret_cast<const float4*>(&Ws[kk][tx*4]);
            float aa[4] = {a4.x, a4.y, a4.z, a4.w};
            float bb[4] = {b4.x, b4.y, b4.z, b4.w};
            #pragma unroll
            for (int i = 0; i < 4; ++i)
                #pragma unroll
                for (int j = 0; j < 4; ++j)
                    acc[i][j] = fmaf(aa[i], bb[j], acc[i][j]);
        }
        __syncthreads();
    }
    #pragma unroll
    for (int i = 0; i < 4; ++i) {
        int row = bm + ty*4 + i;
        #pragma unroll
        for (int j = 0; j < 4; ++j) {
            int col = bn + tx*4 + j;
            if (col < N) {
                float v = acc[i][j];
                if (bias) v += bias[col];
                if (act == 1) v = fmaxf(v, 0.f);
                else if (act == 2) v = fmaxf(v, 0.f) + log1pf(expf(-fabsf(v)));  // softplus
                size_t o = (size_t)row * N + col;
                if (accum) v += C[o];
                C[o] = v;
            }
        }
    }
}

// ---------------- KAN: per-row LN stats over 115 dims ----------------
__global__ __launch_bounds__(256) void kan_stats(const float* __restrict__ obs,
                                                 float* __restrict__ stats)
{
    int row = blockIdx.x * 4 + (threadIdx.x >> 6);
    int lane = threadIdx.x & 63;
    const float* o = obs + (size_t)row * FD;
    float v0 = o[lane];
    float v1 = (lane + 64 < FD) ? o[lane + 64] : 0.f;
    float s = v0 + v1;
    for (int off = 32; off; off >>= 1) s += __shfl_xor(s, off);
    float m = s * (1.f / FD);
    float e0 = v0 - m;
    float e1 = (lane + 64 < FD) ? (v1 - m) : 0.f;
    float ss = e0*e0 + e1*e1;
    for (int off = 32; off; off >>= 1) ss += __shfl_xor(ss, off);
    if (lane == 0) {
        stats[2*row]   = m;
        stats[2*row+1] = rsqrtf(ss * (1.f / FD) + 1e-5f);
    }
}

// ---------------- KAN weight repack: waug[o][k], k=i*2+j (j=0 base, j=1 sum-spline) --
__global__ void prep_waug(const float* __restrict__ sp, const float* __restrict__ sc,
                          float* __restrict__ Wg)
{
    int idx = blockIdx.x * 256 + threadIdx.x;
    if (idx >= DM * KKAN) return;
    int o = idx / KKAN, k = idx - o * KKAN;
    float v = 0.f;
    if (k < KREAL) {
        int i = k >> 1, j = k & 1;
        if (j == 0) v = sc[o*FD + i];
        else {
            const float* s5 = sp + ((size_t)o*FD + i)*5;
            v = s5[0] + s5[1] + s5[2] + s5[3] + s5[4];
        }
    }
    Wg[idx] = v;
}

// ---------------- KAN GEMM: fe[65536,256] = XA[65536,240] @ waug^T + kan_bias --------
// XA generated on the fly: LN'ed obs value (j=0) or sum of 5 Gaussians (j=1).
__global__ __launch_bounds__(256) void kan_gemm(
    const float* __restrict__ obs, const float* __restrict__ stats,
    const float* __restrict__ lng, const float* __restrict__ lnb,
    const float* __restrict__ betap,
    const float* __restrict__ W, const float* __restrict__ bias,
    float* __restrict__ C)
{
    __shared__ float As[16][68];
    __shared__ float Ws[16][68];
    const float beta = fminf(fmaxf(betap[0], 0.5f), 6.0f);
    const int tid = threadIdx.x;
    const int bm = blockIdx.x * 64;
    const int bn = blockIdx.y * 64;
    const int ty = tid >> 4, tx = tid & 15;
    const int lr = tid >> 2;
    const int lk = (tid & 3) * 4;
    const int r = bm + lr;
    const float m  = stats[2*r];
    const float rs = stats[2*r+1];
    const float* orow = obs + (size_t)r * FD;
    float acc[4][4] = {{0.f,0.f,0.f,0.f},{0.f,0.f,0.f,0.f},{0.f,0.f,0.f,0.f},{0.f,0.f,0.f,0.f}};

    for (int k0 = 0; k0 < KKAN; k0 += 16) {
        float vals[4];
        #pragma unroll
        for (int q = 0; q < 4; q += 2) {
            int k = k0 + lk + q;          // even; pair (k, k+1) shares input i
            int i = k >> 1;
            float xv = 0.f, sb = 0.f;
            if (k < KREAL) {
                float x = (orow[i] - m) * rs * lng[i] + lnb[i];
                xv = x;
                #pragma unroll
                for (int g = 0; g < 5; ++g) {
                    float dx = x - (-1.f + 0.5f * (float)g);
                    sb += expf(-dx*dx*beta);
                }
            }
            vals[q] = xv; vals[q+1] = sb;
        }
        As[lk+0][lr]=vals[0]; As[lk+1][lr]=vals[1]; As[lk+2][lr]=vals[2]; As[lk+3][lr]=vals[3];
        float4 wv = *reinterpret_cast<const float4*>(W + (size_t)(bn + lr) * KKAN + k0 + lk);
        Ws[lk+0][lr]=wv.x; Ws[lk+1][lr]=wv.y; Ws[lk+2][lr]=wv.z; Ws[lk+3][lr]=wv.w;
        __syncthreads();
        #pragma unroll
        for (int kk = 0; kk < 16; ++kk) {
            float4 a4 = *reinterpret_cast<const float4*>(&As[kk][ty*4]);
            float4 b4 = *reinterpret_cast<const float4*>(&Ws[kk][tx*4]);
            float aa[4] = {a4.x, a4.y, a4.z, a4.w};
            float bb[4] = {b4.x, b4.y, b4.z, b4.w};
            #pragma unroll
            for (int i = 0; i < 4; ++i)
                #pragma unroll
                for (int j = 0; j < 4; ++j)
                    acc[i][j] = fmaf(aa[i], bb[j], acc[i][j]);
        }
        __syncthreads();
    }
    #pragma unroll
    for (int i = 0; i < 4; ++i) {
        int row = bm + ty*4 + i;
        #pragma unroll
        for (int j = 0; j < 4; ++j) {
            int col = bn + tx*4 + j;
            C[(size_t)row * DM + col] = acc[i][j] + bias[col];
        }
    }
}

// ---------------- fe -> LN(256) -> relu -> mean over 4 frames -> feat (into cat) -----
__global__ __launch_bounds__(256) void fe_reduce(const float* __restrict__ fe,
    const float* __restrict__ g, const float* __restrict__ b, float* __restrict__ out)
{
    __shared__ float accs[4][256];
    int row = blockIdx.x;
    int w = threadIdx.x >> 6, lane = threadIdx.x & 63;
    const float* x = fe + ((size_t)row * NF + w) * DM;
    float4 v = reinterpret_cast<const float4*>(x)[lane];
    float s = v.x + v.y + v.z + v.w;
    for (int off = 32; off; off >>= 1) s += __shfl_xor(s, off);
    float m = s * (1.f / DM);
    float d0 = v.x-m, d1 = v.y-m, d2 = v.z-m, d3 = v.w-m;
    float ss = d0*d0 + d1*d1 + d2*d2 + d3*d3;
    for (int off = 32; off; off >>= 1) ss += __shfl_xor(ss, off);
    float rstd = rsqrtf(ss * (1.f / DM) + 1e-5f);
    int c = lane * 4;
    accs[w][c+0] = fmaxf(d0*rstd*g[c+0] + b[c+0], 0.f);
    accs[w][c+1] = fmaxf(d1*rstd*g[c+1] + b[c+1], 0.f);
    accs[w][c+2] = fmaxf(d2*rstd*g[c+2] + b[c+2], 0.f);
    accs[w][c+3] = fmaxf(d3*rstd*g[c+3] + b[c+3], 0.f);
    __syncthreads();
    int t = threadIdx.x;
    out[(size_t)row * CATD + t] =
        (accs[0][t] + accs[1][t] + accs[2][t] + accs[3][t]) * 0.25f;
}

// ---------------- graph feature (1 wave per row) -> gemb (into cat +256) -------------
__global__ __launch_bounds__(64) void graph_kernel(const float* __restrict__ obs,
    const float* __restrict__ gW, const float* __restrict__ ewp,
    float* __restrict__ out)
{
    __shared__ float px[NP], py[NP];
    __shared__ float nodes[NP][8];
    __shared__ float gxs[NP][GH];
    __shared__ unsigned int msk[NP];
    __shared__ float rden[NP];
    __shared__ float wgt[NP];
    const int row = blockIdx.x;
    const int lane = threadIdx.x;
    const float* fc = obs + ((size_t)row * NF + 3) * FD;
    const float* fp = obs + ((size_t)row * NF + 2) * FD;
    const float ew = ewp[0];

    if (lane < NP) {
        int i = lane;
        float p0, p1, q0, q1;
        if (i < 11) { p0 = fc[3+2*i];  p1 = fc[4+2*i];  q0 = fp[3+2*i];  q1 = fp[4+2*i]; }
        else { int ii = i-11; p0 = fc[25+2*ii]; p1 = fc[26+2*ii]; q0 = fp[25+2*ii]; q1 = fp[26+2*ii]; }
        px[i] = p0; py[i] = p1;
        float bx = fc[0], by = fc[1];
        float bd = sqrtf((p0-bx)*(p0-bx) + (p1-by)*(p1-by));
        nodes[i][0] = p0; nodes[i][1] = p1;
        nodes[i][2] = p0 - q0; nodes[i][3] = p1 - q1;
        nodes[i][4] = (i < 11) ? 0.f : 1.f;
        nodes[i][5] = expf(-2.f * bd);
    }
    __syncthreads();
    if (lane < NP) {
        int base = (lane < 11) ? 0 : 11;
        float cx = 0.f, cy = 0.f;
        for (int j = 0; j < 11; ++j) { cx += px[base+j]; cy += py[base+j]; }
        cx *= (1.f/11.f); cy *= (1.f/11.f);
        nodes[lane][6] = px[lane] - cx;
        nodes[lane][7] = py[lane] - cy;
        unsigned sel = 0;
        for (int k = 0; k < GKN; ++k) {
            float best = 1e30f; int bj = 0;
            for (int j = 0; j < NP; ++j) {
                if (j == lane || ((sel >> j) & 1u)) continue;
                float dx = px[lane]-px[j], dy = py[lane]-py[j];
                float dd = sqrtf(dx*dx + dy*dy);
                if (dd < best) { best = dd; bj = j; }
            }
            sel |= (1u << bj);
        }
        unsigned full = sel | (1u << lane);
        msk[lane] = full;
        rden[lane] = 1.f / fmaxf((float)__popc(full), 1.f);
    }
    __syncthreads();
    for (int idx = lane; idx < NP*GH; idx += 64) {
        int i = idx >> 5, h = idx & 31;
        float s = 0.f;
        #pragma unroll
        for (int f = 0; f < 8; ++f) s += nodes[i][f] * gW[h*8 + f];
        gxs[i][h] = s;
    }
    __syncthreads();
    if (lane < NP) {
        float s = 0.f;
        for (int i = 0; i < NP; ++i) if ((msk[i] >> lane) & 1u) s += rden[i];
        wgt[lane] = (1.f - ew) + ew * s;
    }
    __syncthreads();
    if (lane < GH) {
        float s = 0.f;
        for (int j = 0; j < NP; ++j) s += wgt[j] * gxs[j][lane];
        out[(size_t)row * CATD + DM + lane] = s * (1.f/22.f);
    }
}

// ---------------- action embedding gather (into cat +288) ----------------
__global__ void gather_aemb(const int* __restrict__ pa, const float* __restrict__ emb,
                            float* __restrict__ out)
{
    int idx = blockIdx.x * 256 + threadIdx.x;   // BLR*16 total
    int row = idx >> 4, e = idx & 15;
    out[(size_t)row * CATD + DM + GH + e] = emb[pa[row]*AEM + e];
}

// ---------------- LN over 256 cols, wave per row ----------------
__global__ __launch_bounds__(256) void ln256(const float* __restrict__ X,
    const float* __restrict__ g, const float* __restrict__ b, float* __restrict__ Y)
{
    int row = blockIdx.x * 4 + (threadIdx.x >> 6);
    int lane = threadIdx.x & 63;
    const float* x = X + (size_t)row * DM;
    float4 v = reinterpret_cast<const float4*>(x)[lane];
    float s = v.x + v.y + v.z + v.w;
    for (int off = 32; off; off >>= 1) s += __shfl_xor(s, off);
    float m = s * (1.f / DM);
    float d0 = v.x-m, d1 = v.y-m, d2 = v.z-m, d3 = v.w-m;
    float ss = d0*d0 + d1*d1 + d2*d2 + d3*d3;
    for (int off = 32; off; off >>= 1) ss += __shfl_xor(ss, off);
    float rstd = rsqrtf(ss * (1.f / DM) + 1e-5f);
    int c = lane * 4;
    float4 o4 = make_float4(d0*rstd*g[c+0] + b[c+0],
                            d1*rstd*g[c+1] + b[c+1],
                            d2*rstd*g[c+2] + b[c+2],
                            d3*rstd*g[c+3] + b[c+3]);
    reinterpret_cast<float4*>(Y + (size_t)row * DM)[lane] = o4;
}

// ---------------- S6 selective scan. 16 lanes per (b,d) channel ----------------
__global__ __launch_bounds__(256) void s6_scan(
    const float* __restrict__ dt, const float* __restrict__ xin,
    const float* __restrict__ Bt, const float* __restrict__ Ct,
    const float* __restrict__ Alog, const float* __restrict__ h0,
    float* __restrict__ y, float* __restrict__ hout)
{
    int b = blockIdx.x >> 4;
    int d0 = (blockIdx.x & 15) << 4;
    int c = threadIdx.x >> 4, s = threadIdx.x & 15;
    int d = d0 + c;
    float A = -expf(Alog[d*DS + s]);
    float h = h0[(size_t)b*DM*DS + d*DS + s];
    const float* dtb = dt  + (size_t)b*LL*DM;
    const float* xb  = xin + (size_t)b*LL*DM;
    const float* Bb  = Bt  + (size_t)b*LL*DS;
    const float* Cb  = Ct  + (size_t)b*LL*DS;
    float* yb = y + (size_t)b*LL*DM;
    for (int t = 0; t < LL; ++t) {
        float dtv = dtb[t*DM + d];
        float xv  = xb[t*DM + d];
        float Bv  = Bb[t*DS + s];
        float Cv  = Cb[t*DS + s];
        h = expf(dtv * A) * h + (dtv * xv) * Bv;
        float p = h * Cv;
        p += __shfl_xor(p, 1);
        p += __shfl_xor(p, 2);
        p += __shfl_xor(p, 4);
        p += __shfl_xor(p, 8);
        if (s == 0) yb[t*DM + d] = p;
    }
    hout[(size_t)b*DM*DS + d*DS + s] = h;
}

// ---------------- ssm = y*silu(z) + x_in*D ----------------
__global__ __launch_bounds__(256) void ssm_mix(const float* __restrict__ y,
    const float* __restrict__ z, const float* __restrict__ xin,
    const float* __restrict__ Dp, float* __restrict__ out)
{
    size_t idx = (size_t)blockIdx.x * 256 + threadIdx.x;
    int col = (int)(idx & (DM-1));
    float zv = z[idx];
    float sil = zv / (1.f + expf(-zv));
    out[idx] = y[idx]*sil + xin[idx]*Dp[col];
}

// ---------------- host ----------------
static inline void gemm(hipStream_t st, const float* A, const float* W, const float* bias,
                        float* C, int M, int N, int K, int act, int accum) {
    dim3 g(M/64, (N+63)/64);
    gemm_f32<<<g, 256, 0, st>>>(A, W, bias, C, N, K, act, accum);
}

extern "C" void kernel_launch(void* const* d_in, const int* in_sizes, int n_in,
                              void* d_out, int out_size, void* d_ws, size_t ws_size,
                              hipStream_t stream) {
    (void)in_sizes; (void)n_in; (void)out_size; (void)ws_size;
    const float* obs      = (const float*)d_in[0];
    const int*   pa       = (const int*)d_in[1];
    const float* h0in[2]  = {(const float*)d_in[2], (const float*)d_in[3]};
    const float* kan_ln_g = (const float*)d_in[4];
    const float* kan_ln_b = (const float*)d_in[5];
    const float* kan_sp   = (const float*)d_in[6];
    const float* kan_sc   = (const float*)d_in[7];
    const float* kan_bias = (const float*)d_in[8];
    const float* kan_beta = (const float*)d_in[9];
    const float* fn_g     = (const float*)d_in[10];
    const float* fn_b     = (const float*)d_in[11];
    const float* gnn_W    = (const float*)d_in[12];
    const float* edge_w   = (const float*)d_in[13];
    const float* act_emb  = (const float*)d_in[14];
    const float* W_ip     = (const float*)d_in[15];
    const float* b_ip     = (const float*)d_in[16];
    const float* fl_g     = (const float*)d_in[37];
    const float* fl_b     = (const float*)d_in[38];
    const float* pW1      = (const float*)d_in[39];
    const float* pb1      = (const float*)d_in[40];
    const float* pW2      = (const float*)d_in[41];
    const float* pb2      = (const float*)d_in[42];
    const float* vW1      = (const float*)d_in[43];
    const float* vb1      = (const float*)d_in[44];
    const float* vW2      = (const float*)d_in[45];
    const float* vb2      = (const float*)d_in[46];

    // workspace arena (floats). fe overlays R0..R3 (65536x256 = 4*SZ_BIG, contiguous).
    const size_t SZ_BIG = (size_t)BLR * DM;           // 4194304
    float* ws = (float*)d_ws;
    float* X  = ws;
    float* R0 = X  + SZ_BIG;
    float* R1 = R0 + SZ_BIG;
    float* R2 = R1 + SZ_BIG;
    float* R3 = R2 + SZ_BIG;
    float* R4 = R3 + SZ_BIG;                          // cat buffer BLR x 304
    float* R5 = R4 + (size_t)BLR * CATD;              // Bt|Ct (or kan waug/stats early)
    float* WAUG  = R4;                                // overlay: dead once fe_reduce runs
    float* STATS = R5;                                // overlay: dead once kan_gemm runs

    float* out        = (float*)d_out;
    float* out_logits = out;                          // BLR*19
    float* out_value  = out + (size_t)BLR * NACTN;    // BLR
    float* out_h[2]   = {out + (size_t)BLR*NACTN + BLR,
                         out + (size_t)BLR*NACTN + BLR + (size_t)BB*DM*DS};

    // --- KAN feature path ---
    prep_waug<<<(DM*KKAN + 255)/256, 256, 0, stream>>>(kan_sp, kan_sc, WAUG);
    kan_stats<<<BLR*NF/4, 256, 0, stream>>>(obs, STATS);
    kan_gemm<<<dim3(BLR*NF/64, DM/64), 256, 0, stream>>>(
        obs, STATS, kan_ln_g, kan_ln_b, kan_beta, WAUG, kan_bias, R0);
    fe_reduce<<<BLR, 256, 0, stream>>>(R0, fn_g, fn_b, R4);

    // --- graph + action embedding (fill rest of cat) ---
    graph_kernel<<<BLR, 64, 0, stream>>>(obs, gnn_W, edge_w, R4);
    gather_aemb<<<BLR*AEM/256, 256, 0, stream>>>(pa, act_emb, R4);

    // --- input projection ---
    gemm(stream, R4, W_ip, b_ip, X, BLR, DM, CATD, 0, 0);

    // --- two S6 layers ---
    for (int l = 0; l < 2; ++l) {
        const float* lng  = (const float*)d_in[17 + 10*l + 0];
        const float* lnb  = (const float*)d_in[17 + 10*l + 1];
        const float* Win  = (const float*)d_in[17 + 10*l + 2];
        const float* Wdt  = (const float*)d_in[17 + 10*l + 3];
        const float* bdt  = (const float*)d_in[17 + 10*l + 4];
        const float* Alog = (const float*)d_in[17 + 10*l + 5];
        const float* WBp  = (const float*)d_in[17 + 10*l + 6];
        const float* WCp  = (const float*)d_in[17 + 10*l + 7];
        const float* Dp   = (const float*)d_in[17 + 10*l + 8];
        const float* Wout = (const float*)d_in[17 + 10*l + 9];

        ln256<<<BLR/4, 256, 0, stream>>>(X, lng, lnb, R0);                 // xn
        gemm(stream, R0, Win,           nullptr, R1, BLR, DM, DM, 0, 0);  // x_in
        gemm(stream, R0, Win + DM*DM,   nullptr, R2, BLR, DM, DM, 0, 0);  // z
        gemm(stream, R1, Wdt, bdt, R3, BLR, DM, DM, 2, 0);                // dt (softplus)
        gemm(stream, R1, WBp, nullptr, R5,                BLR, DS, DM, 0, 0); // Bt
        gemm(stream, R1, WCp, nullptr, R5 + (size_t)BLR*DS, BLR, DS, DM, 0, 0); // Ct
        s6_scan<<<BB*16, 256, 0, stream>>>(R3, R1, R5, R5 + (size_t)BLR*DS,
                                           Alog, h0in[l], R0, out_h[l]);  // y -> R0
        ssm_mix<<<BLR, 256, 0, stream>>>(R0, R2, R1, Dp, R2);             // ssm -> R2
        gemm(stream, R2, Wout, nullptr, X, BLR, DM, DM, 0, 1);            // X += ssm@Wout^T
    }

    // --- heads ---
    ln256<<<BLR/4, 256, 0, stream>>>(X, fl_g, fl_b, R0);
    gemm(stream, R0, pW1, pb1, R1, BLR, 128, DM, 1, 0);
    gemm(stream, R1, pW2, pb2, out_logits, BLR, NACTN, 128, 0, 0);
    gemm(stream, R0, vW1, vb1, R2, BLR, 64, DM, 1, 0);
    gemm(stream, R2, vW2, vb2, out_value, BLR, 1, 64, 0, 0);
}

// Round 3
// 1013.695 us; speedup vs baseline: 1.6623x; 1.6623x over previous
//
#include <hip/hip_runtime.h>
#include <math.h>

// ---------------- problem constants ----------------
#define BB   16
#define LL   1024
#define BLR  (BB*LL)        // 16384 rows
#define DM   256
#define DS   16
#define FD   115
#define NF   4
#define NACTN 19
#define GH   32
#define GKN  6
#define AEM  16
#define NP   22
#define CATD 304            // DM + GH + AEM
#define KKAN 240            // 230 padded to x16
#define KREAL 230           // 115 inputs x {ln_x, sum_basis}
#define NC   8              // scan chunks
#define CL   (LL/NC)        // 128 steps per chunk

// NOTE on the KAN: the reference einsum 'big,oid->bo' has MISMATCHED grid
// subscripts (g vs d), so it computes (sum_g basis) * (sum_d Wsp) contracted
// over i only. Effective per-input features: [x_ln, sum_g exp(-(x_ln-g)^2 b)]
// against weights [kan_scale[o,i], sum_d kan_spline[o,i,d]].

// ---------------- generic f32 GEMM: C[M,N] = act(A[M,K] @ W[N,K]^T + bias) (+C) ----
// 64x64 tile, 256 threads, 4x4 microtile, K step 16. M%64==0, K%16==0. N arbitrary.
__global__ __launch_bounds__(256) void gemm_f32(
    const float* __restrict__ A, const float* __restrict__ W,
    const float* __restrict__ bias, float* __restrict__ C,
    int N, int K, int lda, int ldc, int act, int accum)
{
    __shared__ float As[16][68];
    __shared__ float Ws[16][68];
    const int tid = threadIdx.x;
    const int bm = blockIdx.x * 64;
    const int bn = blockIdx.y * 64;
    const int ty = tid >> 4, tx = tid & 15;
    const int lr = tid >> 2;            // 0..63 tile row
    const int lk = (tid & 3) * 4;       // 0,4,8,12
    float acc[4][4] = {{0.f,0.f,0.f,0.f},{0.f,0.f,0.f,0.f},{0.f,0.f,0.f,0.f},{0.f,0.f,0.f,0.f}};

    for (int k0 = 0; k0 < K; k0 += 16) {
        float4 av = *reinterpret_cast<const float4*>(A + (size_t)(bm + lr) * lda + k0 + lk);
        As[lk+0][lr] = av.x; As[lk+1][lr] = av.y; As[lk+2][lr] = av.z; As[lk+3][lr] = av.w;
        float4 wv = make_float4(0.f, 0.f, 0.f, 0.f);
        if (bn + lr < N)
            wv = *reinterpret_cast<const float4*>(W + (size_t)(bn + lr) * K + k0 + lk);
        Ws[lk+0][lr] = wv.x; Ws[lk+1][lr] = wv.y; Ws[lk+2][lr] = wv.z; Ws[lk+3][lr] = wv.w;
        __syncthreads();
        #pragma unroll
        for (int kk = 0; kk < 16; ++kk) {
            float4 a4 = *reinterpret_cast<const float4*>(&As[kk][ty*4]);
            float4 b4 = *reinterpret_cast<const float4*>(&Ws[kk][tx*4]);
            float aa[4] = {a4.x, a4.y, a4.z, a4.w};
            float bb[4] = {b4.x, b4.y, b4.z, b4.w};
            #pragma unroll
            for (int i = 0; i < 4; ++i)
                #pragma unroll
                for (int j = 0; j < 4; ++j)
                    acc[i][j] = fmaf(aa[i], bb[j], acc[i][j]);
        }
        __syncthreads();
    }
    #pragma unroll
    for (int i = 0; i < 4; ++i) {
        int row = bm + ty*4 + i;
        #pragma unroll
        for (int j = 0; j < 4; ++j) {
            int col = bn + tx*4 + j;
            if (col < N) {
                float v = acc[i][j];
                if (bias) v += bias[col];
                if (act == 1) v = fmaxf(v, 0.f);
                else if (act == 2) v = fmaxf(v, 0.f) + log1pf(expf(-fabsf(v)));  // softplus
                size_t o = (size_t)row * ldc + col;
                if (accum) v += C[o];
                C[o] = v;
            }
        }
    }
}

// ---------------- KAN: per-row LN stats over 115 dims ----------------
__global__ __launch_bounds__(256) void kan_stats(const float* __restrict__ obs,
                                                 float* __restrict__ stats)
{
    int row = blockIdx.x * 4 + (threadIdx.x >> 6);
    int lane = threadIdx.x & 63;
    const float* o = obs + (size_t)row * FD;
    float v0 = o[lane];
    float v1 = (lane + 64 < FD) ? o[lane + 64] : 0.f;
    float s = v0 + v1;
    for (int off = 32; off; off >>= 1) s += __shfl_xor(s, off);
    float m = s * (1.f / FD);
    float e0 = v0 - m;
    float e1 = (lane + 64 < FD) ? (v1 - m) : 0.f;
    float ss = e0*e0 + e1*e1;
    for (int off = 32; off; off >>= 1) ss += __shfl_xor(ss, off);
    if (lane == 0) {
        stats[2*row]   = m;
        stats[2*row+1] = rsqrtf(ss * (1.f / FD) + 1e-5f);
    }
}

// ---------------- KAN weight repack: waug[o][k], k=i*2+j (j=0 base, j=1 sum-spline) --
__global__ void prep_waug(const float* __restrict__ sp, const float* __restrict__ sc,
                          float* __restrict__ Wg)
{
    int idx = blockIdx.x * 256 + threadIdx.x;
    if (idx >= DM * KKAN) return;
    int o = idx / KKAN, k = idx - o * KKAN;
    float v = 0.f;
    if (k < KREAL) {
        int i = k >> 1, j = k & 1;
        if (j == 0) v = sc[o*FD + i];
        else {
            const float* s5 = sp + ((size_t)o*FD + i)*5;
            v = s5[0] + s5[1] + s5[2] + s5[3] + s5[4];
        }
    }
    Wg[idx] = v;
}

// ---------------- WB|WC repack into [32][256] ----------------
__global__ void prep_wbc(const float* __restrict__ WB, const float* __restrict__ WC,
                         float* __restrict__ Wg)
{
    int idx = blockIdx.x * 256 + threadIdx.x;   // 32*256
    if (idx >= 32 * DM) return;
    int n = idx >> 8, k = idx & 255;
    Wg[idx] = (n < 16) ? WB[n*DM + k] : WC[(n-16)*DM + k];
}

// ---------------- KAN GEMM: fe[65536,256] = XA[65536,240] @ waug^T + kan_bias --------
__global__ __launch_bounds__(256) void kan_gemm(
    const float* __restrict__ obs, const float* __restrict__ stats,
    const float* __restrict__ lng, const float* __restrict__ lnb,
    const float* __restrict__ betap,
    const float* __restrict__ W, const float* __restrict__ bias,
    float* __restrict__ C)
{
    __shared__ float As[16][68];
    __shared__ float Ws[16][68];
    const float beta = fminf(fmaxf(betap[0], 0.5f), 6.0f);
    const int tid = threadIdx.x;
    const int bm = blockIdx.x * 64;
    const int bn = blockIdx.y * 64;
    const int ty = tid >> 4, tx = tid & 15;
    const int lr = tid >> 2;
    const int lk = (tid & 3) * 4;
    const int r = bm + lr;
    const float m  = stats[2*r];
    const float rs = stats[2*r+1];
    const float* orow = obs + (size_t)r * FD;
    float acc[4][4] = {{0.f,0.f,0.f,0.f},{0.f,0.f,0.f,0.f},{0.f,0.f,0.f,0.f},{0.f,0.f,0.f,0.f}};

    for (int k0 = 0; k0 < KKAN; k0 += 16) {
        float vals[4];
        #pragma unroll
        for (int q = 0; q < 4; q += 2) {
            int k = k0 + lk + q;          // even; pair (k, k+1) shares input i
            int i = k >> 1;
            float xv = 0.f, sb = 0.f;
            if (k < KREAL) {
                float x = (orow[i] - m) * rs * lng[i] + lnb[i];
                xv = x;
                #pragma unroll
                for (int g = 0; g < 5; ++g) {
                    float dx = x - (-1.f + 0.5f * (float)g);
                    sb += expf(-dx*dx*beta);
                }
            }
            vals[q] = xv; vals[q+1] = sb;
        }
        As[lk+0][lr]=vals[0]; As[lk+1][lr]=vals[1]; As[lk+2][lr]=vals[2]; As[lk+3][lr]=vals[3];
        float4 wv = *reinterpret_cast<const float4*>(W + (size_t)(bn + lr) * KKAN + k0 + lk);
        Ws[lk+0][lr]=wv.x; Ws[lk+1][lr]=wv.y; Ws[lk+2][lr]=wv.z; Ws[lk+3][lr]=wv.w;
        __syncthreads();
        #pragma unroll
        for (int kk = 0; kk < 16; ++kk) {
            float4 a4 = *reinterpret_cast<const float4*>(&As[kk][ty*4]);
            float4 b4 = *reinterpret_cast<const float4*>(&Ws[kk][tx*4]);
            float aa[4] = {a4.x, a4.y, a4.z, a4.w};
            float bb[4] = {b4.x, b4.y, b4.z, b4.w};
            #pragma unroll
            for (int i = 0; i < 4; ++i)
                #pragma unroll
                for (int j = 0; j < 4; ++j)
                    acc[i][j] = fmaf(aa[i], bb[j], acc[i][j]);
        }
        __syncthreads();
    }
    #pragma unroll
    for (int i = 0; i < 4; ++i) {
        int row = bm + ty*4 + i;
        #pragma unroll
        for (int j = 0; j < 4; ++j) {
            int col = bn + tx*4 + j;
            C[(size_t)row * DM + col] = acc[i][j] + bias[col];
        }
    }
}

// ---------------- fe -> LN(256) -> relu -> mean over 4 frames -> feat (into cat) -----
__global__ __launch_bounds__(256) void fe_reduce(const float* __restrict__ fe,
    const float* __restrict__ g, const float* __restrict__ b, float* __restrict__ out)
{
    __shared__ float accs[4][256];
    int row = blockIdx.x;
    int w = threadIdx.x >> 6, lane = threadIdx.x & 63;
    const float* x = fe + ((size_t)row * NF + w) * DM;
    float4 v = reinterpret_cast<const float4*>(x)[lane];
    float s = v.x + v.y + v.z + v.w;
    for (int off = 32; off; off >>= 1) s += __shfl_xor(s, off);
    float m = s * (1.f / DM);
    float d0 = v.x-m, d1 = v.y-m, d2 = v.z-m, d3 = v.w-m;
    float ss = d0*d0 + d1*d1 + d2*d2 + d3*d3;
    for (int off = 32; off; off >>= 1) ss += __shfl_xor(ss, off);
    float rstd = rsqrtf(ss * (1.f / DM) + 1e-5f);
    int c = lane * 4;
    accs[w][c+0] = fmaxf(d0*rstd*g[c+0] + b[c+0], 0.f);
    accs[w][c+1] = fmaxf(d1*rstd*g[c+1] + b[c+1], 0.f);
    accs[w][c+2] = fmaxf(d2*rstd*g[c+2] + b[c+2], 0.f);
    accs[w][c+3] = fmaxf(d3*rstd*g[c+3] + b[c+3], 0.f);
    __syncthreads();
    int t = threadIdx.x;
    out[(size_t)row * CATD + t] =
        (accs[0][t] + accs[1][t] + accs[2][t] + accs[3][t]) * 0.25f;
}

// ---------------- graph feature (1 wave per row) -> gemb (into cat +256) -------------
__global__ __launch_bounds__(64) void graph_kernel(const float* __restrict__ obs,
    const float* __restrict__ gW, const float* __restrict__ ewp,
    float* __restrict__ out)
{
    __shared__ float px[NP], py[NP];
    __shared__ float nodes[NP][8];
    __shared__ float gxs[NP][GH];
    __shared__ unsigned int msk[NP];
    __shared__ float rden[NP];
    __shared__ float wgt[NP];
    const int row = blockIdx.x;
    const int lane = threadIdx.x;
    const float* fc = obs + ((size_t)row * NF + 3) * FD;
    const float* fp = obs + ((size_t)row * NF + 2) * FD;
    const float ew = ewp[0];

    if (lane < NP) {
        int i = lane;
        float p0, p1, q0, q1;
        if (i < 11) { p0 = fc[3+2*i];  p1 = fc[4+2*i];  q0 = fp[3+2*i];  q1 = fp[4+2*i]; }
        else { int ii = i-11; p0 = fc[25+2*ii]; p1 = fc[26+2*ii]; q0 = fp[25+2*ii]; q1 = fp[26+2*ii]; }
        px[i] = p0; py[i] = p1;
        float bx = fc[0], by = fc[1];
        float bd = sqrtf((p0-bx)*(p0-bx) + (p1-by)*(p1-by));
        nodes[i][0] = p0; nodes[i][1] = p1;
        nodes[i][2] = p0 - q0; nodes[i][3] = p1 - q1;
        nodes[i][4] = (i < 11) ? 0.f : 1.f;
        nodes[i][5] = expf(-2.f * bd);
    }
    __syncthreads();
    if (lane < NP) {
        int base = (lane < 11) ? 0 : 11;
        float cx = 0.f, cy = 0.f;
        for (int j = 0; j < 11; ++j) { cx += px[base+j]; cy += py[base+j]; }
        cx *= (1.f/11.f); cy *= (1.f/11.f);
        nodes[lane][6] = px[lane] - cx;
        nodes[lane][7] = py[lane] - cy;
        unsigned sel = 0;
        for (int k = 0; k < GKN; ++k) {
            float best = 1e30f; int bj = 0;
            for (int j = 0; j < NP; ++j) {
                if (j == lane || ((sel >> j) & 1u)) continue;
                float dx = px[lane]-px[j], dy = py[lane]-py[j];
                float dd = sqrtf(dx*dx + dy*dy);
                if (dd < best) { best = dd; bj = j; }
            }
            sel |= (1u << bj);
        }
        unsigned full = sel | (1u << lane);
        msk[lane] = full;
        rden[lane] = 1.f / fmaxf((float)__popc(full), 1.f);
    }
    __syncthreads();
    for (int idx = lane; idx < NP*GH; idx += 64) {
        int i = idx >> 5, h = idx & 31;
        float s = 0.f;
        #pragma unroll
        for (int f = 0; f < 8; ++f) s += nodes[i][f] * gW[h*8 + f];
        gxs[i][h] = s;
    }
    __syncthreads();
    if (lane < NP) {
        float s = 0.f;
        for (int i = 0; i < NP; ++i) if ((msk[i] >> lane) & 1u) s += rden[i];
        wgt[lane] = (1.f - ew) + ew * s;
    }
    __syncthreads();
    if (lane < GH) {
        float s = 0.f;
        for (int j = 0; j < NP; ++j) s += wgt[j] * gxs[j][lane];
        out[(size_t)row * CATD + DM + lane] = s * (1.f/22.f);
    }
}

// ---------------- action embedding gather (into cat +288) ----------------
__global__ void gather_aemb(const int* __restrict__ pa, const float* __restrict__ emb,
                            float* __restrict__ out)
{
    int idx = blockIdx.x * 256 + threadIdx.x;   // BLR*16 total
    int row = idx >> 4, e = idx & 15;
    out[(size_t)row * CATD + DM + GH + e] = emb[pa[row]*AEM + e];
}

// ---------------- LN over 256 cols, wave per row ----------------
__global__ __launch_bounds__(256) void ln256(const float* __restrict__ X,
    const float* __restrict__ g, const float* __restrict__ b, float* __restrict__ Y)
{
    int row = blockIdx.x * 4 + (threadIdx.x >> 6);
    int lane = threadIdx.x & 63;
    const float* x = X + (size_t)row * DM;
    float4 v = reinterpret_cast<const float4*>(x)[lane];
    float s = v.x + v.y + v.z + v.w;
    for (int off = 32; off; off >>= 1) s += __shfl_xor(s, off);
    float m = s * (1.f / DM);
    float d0 = v.x-m, d1 = v.y-m, d2 = v.z-m, d3 = v.w-m;
    float ss = d0*d0 + d1*d1 + d2*d2 + d3*d3;
    for (int off = 32; off; off >>= 1) ss += __shfl_xor(ss, off);
    float rstd = rsqrtf(ss * (1.f / DM) + 1e-5f);
    int c = lane * 4;
    float4 o4 = make_float4(d0*rstd*g[c+0] + b[c+0],
                            d1*rstd*g[c+1] + b[c+1],
                            d2*rstd*g[c+2] + b[c+2],
                            d3*rstd*g[c+3] + b[c+3]);
    reinterpret_cast<float4*>(Y + (size_t)row * DM)[lane] = o4;
}

// ======== S6 chunked parallel scan ========
// h_t = exp(dt*A)*h + dt*x*B ;  y_t = sum_s h*C
// Phase A: per (b,chunk,d,s): P = prod dA, S = scan with h0=0.
// Phase B: per (b,d,s): sequential combine over NC chunks -> per-chunk h_init, final h.
// Phase C: replay chunk from h_init, fuse y*silu(z)+x*D into ssm output.

__global__ __launch_bounds__(256) void s6_chunkA(
    const float* __restrict__ dt, const float* __restrict__ xz,
    const float* __restrict__ bc, const float* __restrict__ Alog,
    float* __restrict__ P, float* __restrict__ S)
{
    const int blk = blockIdx.x;              // 16b x 8c x 16dblk
    const int dblk = blk & 15, c = (blk >> 4) & 7, b = blk >> 7;
    const int s = threadIdx.x & 15, dl = threadIdx.x >> 4;
    const int d = dblk*16 + dl;
    const float A = -expf(Alog[d*DS + s]);
    const size_t r0 = (size_t)b*LL + c*CL;
    float Pv = 1.f, Sv = 0.f;
    for (int t = 0; t < CL; ++t) {
        size_t r = r0 + t;
        float dtv = dt[r*DM + d];
        float xv  = xz[r*512 + d];
        float Bv  = bc[r*32 + s];
        float dA  = expf(dtv * A);
        Pv *= dA;
        Sv = fmaf(dA, Sv, dtv * xv * Bv);
    }
    size_t o = (((size_t)b*NC + c)*DM + d)*DS + s;
    P[o] = Pv; S[o] = Sv;
}

__global__ __launch_bounds__(256) void s6_comb(
    const float* __restrict__ P, const float* __restrict__ S,
    const float* __restrict__ h0, float* __restrict__ hin, float* __restrict__ hout)
{
    int idx = blockIdx.x * 256 + threadIdx.x;   // b*4096 + d*16 + s
    int b = idx >> 12, ds = idx & 4095;
    float h = h0[idx];
    #pragma unroll
    for (int c = 0; c < NC; ++c) {
        size_t o = (((size_t)b*NC + c) << 12) + ds;
        hin[o] = h;
        h = fmaf(P[o], h, S[o]);
    }
    hout[idx] = h;
}

__global__ __launch_bounds__(256) void s6_chunkC(
    const float* __restrict__ dt, const float* __restrict__ xz,
    const float* __restrict__ bc, const float* __restrict__ Alog,
    const float* __restrict__ hin, const float* __restrict__ Dp,
    float* __restrict__ ssm)
{
    const int blk = blockIdx.x;
    const int dblk = blk & 15, c = (blk >> 4) & 7, b = blk >> 7;
    const int s = threadIdx.x & 15, dl = threadIdx.x >> 4;
    const int d = dblk*16 + dl;
    const float A = -expf(Alog[d*DS + s]);
    const float Dv = Dp[d];
    const size_t r0 = (size_t)b*LL + c*CL;
    float h = hin[(((size_t)b*NC + c)*DM + d)*DS + s];
    for (int t = 0; t < CL; ++t) {
        size_t r = r0 + t;
        float dtv = dt[r*DM + d];        // read BEFORE ssm store to same addr (same wave)
        float xv  = xz[r*512 + d];
        float Bv  = bc[r*32 + s];
        float Cv  = bc[r*32 + 16 + s];
        float dA  = expf(dtv * A);
        h = fmaf(dA, h, dtv * xv * Bv);
        float p = h * Cv;
        p += __shfl_xor(p, 1);
        p += __shfl_xor(p, 2);
        p += __shfl_xor(p, 4);
        p += __shfl_xor(p, 8);
        if (s == 0) {
            float zv = xz[r*512 + 256 + d];
            float sil = zv / (1.f + expf(-zv));
            ssm[r*DM + d] = fmaf(p, sil, xv * Dv);
        }
    }
}

// ---------------- host ----------------
static inline void gemm(hipStream_t st, const float* A, const float* W, const float* bias,
                        float* C, int M, int N, int K, int lda, int ldc, int act, int accum) {
    dim3 g(M/64, (N+63)/64);
    gemm_f32<<<g, 256, 0, st>>>(A, W, bias, C, N, K, lda, ldc, act, accum);
}

extern "C" void kernel_launch(void* const* d_in, const int* in_sizes, int n_in,
                              void* d_out, int out_size, void* d_ws, size_t ws_size,
                              hipStream_t stream) {
    (void)in_sizes; (void)n_in; (void)out_size; (void)ws_size;
    const float* obs      = (const float*)d_in[0];
    const int*   pa       = (const int*)d_in[1];
    const float* h0in[2]  = {(const float*)d_in[2], (const float*)d_in[3]};
    const float* kan_ln_g = (const float*)d_in[4];
    const float* kan_ln_b = (const float*)d_in[5];
    const float* kan_sp   = (const float*)d_in[6];
    const float* kan_sc   = (const float*)d_in[7];
    const float* kan_bias = (const float*)d_in[8];
    const float* kan_beta = (const float*)d_in[9];
    const float* fn_g     = (const float*)d_in[10];
    const float* fn_b     = (const float*)d_in[11];
    const float* gnn_W    = (const float*)d_in[12];
    const float* edge_w   = (const float*)d_in[13];
    const float* act_emb  = (const float*)d_in[14];
    const float* W_ip     = (const float*)d_in[15];
    const float* b_ip     = (const float*)d_in[16];
    const float* fl_g     = (const float*)d_in[37];
    const float* fl_b     = (const float*)d_in[38];
    const float* pW1      = (const float*)d_in[39];
    const float* pb1      = (const float*)d_in[40];
    const float* pW2      = (const float*)d_in[41];
    const float* pb2      = (const float*)d_in[42];
    const float* vW1      = (const float*)d_in[43];
    const float* vb1      = (const float*)d_in[44];
    const float* vW2      = (const float*)d_in[45];
    const float* vb2      = (const float*)d_in[46];

    // workspace arena (floats)
    const size_t SZ_BIG = (size_t)BLR * DM;           // 4194304
    float* ws = (float*)d_ws;
    float* X  = ws;                                   // residual stream
    float* R0 = X  + SZ_BIG;                          // xn / fe part
    float* R1 = R0 + SZ_BIG;                          // XZ lo   / fe part
    float* R2 = R1 + SZ_BIG;                          // XZ hi   / fe part
    float* R3 = R2 + SZ_BIG;                          // dt->ssm / fe part
    float* R4 = R3 + SZ_BIG;                          // cat BLRx304; later P|S|HIN
    float* R5 = R4 + (size_t)BLR * CATD;              // BC BLRx32
    float* WBC = R5 + (size_t)BLR * 32;               // 32x256 repack
    float* FE  = R0;                                  // fe occupies R0..R3 (65536x256)
    float* XZ  = R1;                                  // BLR x 512 (x_in | z)
    float* WAUG  = R4;                                // overlay pre-cat
    float* STATS = R5;                                // overlay pre-cat
    const size_t CH = (size_t)BB * NC * DM * DS;      // 524288
    float* Pbuf = R4;                                 // overlays dead cat
    float* Sbuf = R4 + CH;
    float* HIN  = R4 + 2*CH;

    float* out        = (float*)d_out;
    float* out_logits = out;                          // BLR*19
    float* out_value  = out + (size_t)BLR * NACTN;    // BLR
    float* out_h[2]   = {out + (size_t)BLR*NACTN + BLR,
                         out + (size_t)BLR*NACTN + BLR + (size_t)BB*DM*DS};

    // --- KAN feature path ---
    prep_waug<<<(DM*KKAN + 255)/256, 256, 0, stream>>>(kan_sp, kan_sc, WAUG);
    kan_stats<<<BLR*NF/4, 256, 0, stream>>>(obs, STATS);
    kan_gemm<<<dim3(BLR*NF/64, DM/64), 256, 0, stream>>>(
        obs, STATS, kan_ln_g, kan_ln_b, kan_beta, WAUG, kan_bias, FE);
    fe_reduce<<<BLR, 256, 0, stream>>>(FE, fn_g, fn_b, R4);

    // --- graph + action embedding (fill rest of cat) ---
    graph_kernel<<<BLR, 64, 0, stream>>>(obs, gnn_W, edge_w, R4);
    gather_aemb<<<BLR*AEM/256, 256, 0, stream>>>(pa, act_emb, R4);

    // --- input projection ---
    gemm(stream, R4, W_ip, b_ip, X, BLR, DM, CATD, CATD, DM, 0, 0);

    // --- two S6 layers ---
    for (int l = 0; l < 2; ++l) {
        const float* lng  = (const float*)d_in[17 + 10*l + 0];
        const float* lnb  = (const float*)d_in[17 + 10*l + 1];
        const float* Win  = (const float*)d_in[17 + 10*l + 2];
        const float* Wdt  = (const float*)d_in[17 + 10*l + 3];
        const float* bdt  = (const float*)d_in[17 + 10*l + 4];
        const float* Alog = (const float*)d_in[17 + 10*l + 5];
        const float* WBp  = (const float*)d_in[17 + 10*l + 6];
        const float* WCp  = (const float*)d_in[17 + 10*l + 7];
        const float* Dp   = (const float*)d_in[17 + 10*l + 8];
        const float* Wout = (const float*)d_in[17 + 10*l + 9];

        ln256<<<BLR/4, 256, 0, stream>>>(X, lng, lnb, R0);                     // xn
        gemm(stream, R0, Win, nullptr, XZ, BLR, 512, DM, DM, 512, 0, 0);       // x_in|z
        gemm(stream, XZ, Wdt, bdt, R3, BLR, DM, DM, 512, DM, 2, 0);            // dt
        prep_wbc<<<32, 256, 0, stream>>>(WBp, WCp, WBC);
        gemm(stream, XZ, WBC, nullptr, R5, BLR, 32, DM, 512, 32, 0, 0);        // Bt|Ct
        s6_chunkA<<<BB*NC*16, 256, 0, stream>>>(R3, XZ, R5, Alog, Pbuf, Sbuf);
        s6_comb<<<BB*DM*DS/256, 256, 0, stream>>>(Pbuf, Sbuf, h0in[l], HIN, out_h[l]);
        s6_chunkC<<<BB*NC*16, 256, 0, stream>>>(R3, XZ, R5, Alog, HIN, Dp, R3); // ssm -> R3
        gemm(stream, R3, Wout, nullptr, X, BLR, DM, DM, DM, DM, 0, 1);         // X += ssm@Wout^T
    }

    // --- heads ---
    ln256<<<BLR/4, 256, 0, stream>>>(X, fl_g, fl_b, R0);
    gemm(stream, R0, pW1, pb1, R1, BLR, 128, DM, DM, 128, 1, 0);
    gemm(stream, R1, pW2, pb2, out_logits, BLR, NACTN, 128, 128, NACTN, 0, 0);
    gemm(stream, R0, vW1, vb1, R2, BLR, 64, DM, DM, 64, 1, 0);
    gemm(stream, R2, vW2, vb2, out_value, BLR, 1, 64, 64, 1, 0, 0);
}

// Round 6
// 825.633 us; speedup vs baseline: 2.0409x; 1.2278x over previous
//
#include <hip/hip_runtime.h>
#include <math.h>

// ---------------- problem constants ----------------
#define BB   16
#define LL   1024
#define BLR  (BB*LL)        // 16384 rows
#define DM   256
#define DS   16
#define FD   115
#define NF   4
#define NACTN 19
#define GH   32
#define GKN  6
#define AEM  16
#define NP   22
#define CATD 304            // cat width (16-aligned, NOT padded)
#define CATP 320            // MFMA Kp for input proj (zero-pad in weights + Kreal guard)
#define KKANP 256           // KAN K padded to x32
#define KREALK 230          // 115 inputs x {ln_x, sum_basis}
#define NC   8              // scan chunks
#define CL   (LL/NC)        // 128 steps per chunk
#define LDK  40             // LDS row stride in bf16 elems (32 + pad, 80B = 5x16B aligned)

// NOTE on the KAN: the reference einsum 'big,oid->bo' has MISMATCHED grid
// subscripts (g vs d) -> contraction over i only with (sum_g basis)*(sum_d Wsp).

typedef __attribute__((ext_vector_type(8))) short bf16x8;
typedef __attribute__((ext_vector_type(4))) float f32x4;

__device__ inline unsigned short f2bf(float f) {
    unsigned int u = __float_as_uint(f);
    u += 0x7fff + ((u >> 16) & 1);
    return (unsigned short)(u >> 16);
}
__device__ inline unsigned int f2bf2(float lo, float hi) {
    return (unsigned int)f2bf(lo) | ((unsigned int)f2bf(hi) << 16);
}

// ============ MFMA GEMM: C[M,N] = act(A_f32[M,Kreal] @ W_bf16[N,Kp]^T + bias) (+C) ==
// 128x128 tile, 256 threads (4 waves 2x2), BK=32, mfma_f32_16x16x32_bf16.
// Each thread stages 16 shorts of A AND 16 shorts of W (2x uint4 each).
// R4/R5 bug fix: W-stage previously copied only 8 shorts -> uninit LDS -> NaN.
__global__ __launch_bounds__(256) void mfma_gemm(
    const float* __restrict__ A, const unsigned short* __restrict__ W,
    const float* __restrict__ bias, float* __restrict__ C,
    int N, int Kp, int Kreal, int lda, int ldc, int act, int accum)
{
    __shared__ __align__(16) unsigned short As[128*LDK];
    __shared__ __align__(16) unsigned short Ws[128*LDK];
    const int tid = threadIdx.x;
    const int bm = blockIdx.x * 128;
    const int bn = blockIdx.y * 128;
    const int wid = tid >> 6, lane = tid & 63;
    const int wr = wid >> 1, wc = wid & 1;
    const int g = lane >> 4, r16 = lane & 15;
    const int srow = tid >> 1;            // 0..127
    const int shalf = (tid & 1) * 16;     // k offset 0/16

    f32x4 acc[4][4] = {};
    for (int k0 = 0; k0 < Kp; k0 += 32) {
        // --- stage A (f32 -> bf16): 16 floats -> 16 shorts ---
        uint4 alo = make_uint4(0u,0u,0u,0u), ahi = make_uint4(0u,0u,0u,0u);
        if (k0 + shalf < Kreal) {
            const float* ap = A + (size_t)(bm + srow) * lda + k0 + shalf;
            float4 a0 = *(const float4*)(ap);
            float4 a1 = *(const float4*)(ap + 4);
            float4 a2 = *(const float4*)(ap + 8);
            float4 a3 = *(const float4*)(ap + 12);
            alo = make_uint4(f2bf2(a0.x,a0.y), f2bf2(a0.z,a0.w),
                             f2bf2(a1.x,a1.y), f2bf2(a1.z,a1.w));
            ahi = make_uint4(f2bf2(a2.x,a2.y), f2bf2(a2.z,a2.w),
                             f2bf2(a3.x,a3.y), f2bf2(a3.z,a3.w));
        }
        unsigned short* ad = &As[srow*LDK + shalf];
        *(uint4*)(ad)     = alo;
        *(uint4*)(ad + 8) = ahi;
        // --- stage W (bf16): 16 shorts = 2x uint4 ---
        int n = bn + srow;
        uint4 wv0 = make_uint4(0u,0u,0u,0u), wv1 = make_uint4(0u,0u,0u,0u);
        if (n < N) {
            const unsigned short* wp = W + (size_t)n * Kp + k0 + shalf;
            wv0 = ((const uint4*)wp)[0];   // shorts 0..7
            wv1 = ((const uint4*)wp)[1];   // shorts 8..15
        }
        unsigned short* wd = &Ws[srow*LDK + shalf];
        *(uint4*)(wd)     = wv0;
        *(uint4*)(wd + 8) = wv1;
        __syncthreads();

        bf16x8 af[4], bfr[4];
        #pragma unroll
        for (int mi = 0; mi < 4; ++mi)
            af[mi] = *reinterpret_cast<const bf16x8*>(&As[(wr*64 + mi*16 + r16)*LDK + g*8]);
        #pragma unroll
        for (int ni = 0; ni < 4; ++ni)
            bfr[ni] = *reinterpret_cast<const bf16x8*>(&Ws[(wc*64 + ni*16 + r16)*LDK + g*8]);
        #pragma unroll
        for (int mi = 0; mi < 4; ++mi)
            #pragma unroll
            for (int ni = 0; ni < 4; ++ni)
                acc[mi][ni] = __builtin_amdgcn_mfma_f32_16x16x32_bf16(
                    af[mi], bfr[ni], acc[mi][ni], 0, 0, 0);
        __syncthreads();
    }
    #pragma unroll
    for (int mi = 0; mi < 4; ++mi) {
        #pragma unroll
        for (int j = 0; j < 4; ++j) {
            int row = bm + wr*64 + mi*16 + g*4 + j;
            float* crow = C + (size_t)row * ldc;
            #pragma unroll
            for (int ni = 0; ni < 4; ++ni) {
                int col = bn + wc*64 + ni*16 + r16;
                if (col < N) {
                    float v = acc[mi][ni][j];
                    if (bias) v += bias[col];
                    if (act == 1) v = fmaxf(v, 0.f);
                    else if (act == 2) v = fmaxf(v, 0.f) + log1pf(expf(-fabsf(v)));
                    if (accum) v += crow[col];
                    crow[col] = v;
                }
            }
        }
    }
}

// ============ fused KAN: MFMA(gen(A), WAUG) + bias -> LN(256) -> relu -> frame-mean ==
// 128 fe-rows x 256 cols per block; 4 waves 2x2 (wave = 64 rows x 128 cols).
// 4 consecutive fe-rows (= the j regs of one acc) are the 4 frames of one BL row.
__global__ __launch_bounds__(256) void kan_fused(
    const float* __restrict__ obs, const float* __restrict__ stats,
    const float* __restrict__ lng, const float* __restrict__ lnb,
    const float* __restrict__ betap, const unsigned short* __restrict__ W,
    const float* __restrict__ kbias, const float* __restrict__ fng,
    const float* __restrict__ fnb, float* __restrict__ cat)
{
    __shared__ __align__(16) unsigned short As[128*LDK];
    __shared__ __align__(16) unsigned short Ws[256*LDK];
    __shared__ float rsum[128][2];
    __shared__ float rsq[128][2];
    const float beta = fminf(fmaxf(betap[0], 0.5f), 6.0f);
    const int tid = threadIdx.x;
    const int bm = blockIdx.x * 128;
    const int wid = tid >> 6, lane = tid & 63;
    const int wr = wid >> 1, wc = wid & 1;
    const int g = lane >> 4, r16 = lane & 15;
    const int srow = tid >> 1;
    const int shalf = (tid & 1) * 16;
    const int r = bm + srow;
    const float m  = stats[2*r];
    const float rs = stats[2*r+1];
    const float* orow = obs + (size_t)r * FD;

    f32x4 acc[4][8] = {};
    for (int k0 = 0; k0 < KKANP; k0 += 32) {
        // --- generate A half-row (16 bf16 = 8 input dims) ---
        int i0 = (k0 + shalf) >> 1;
        unsigned int pk[8];
        #pragma unroll
        for (int q = 0; q < 8; ++q) {
            int i = i0 + q;
            float xv = 0.f, sb = 0.f;
            if (i < FD) {
                float x = (orow[i] - m) * rs * lng[i] + lnb[i];
                xv = x;
                #pragma unroll
                for (int g5 = 0; g5 < 5; ++g5) {
                    float dx = x - (-1.f + 0.5f * (float)g5);
                    sb += expf(-dx*dx*beta);
                }
            }
            pk[q] = f2bf2(xv, sb);
        }
        unsigned short* ad = &As[srow*LDK + shalf];
        *(uint4*)(ad)     = make_uint4(pk[0], pk[1], pk[2], pk[3]);
        *(uint4*)(ad + 8) = make_uint4(pk[4], pk[5], pk[6], pk[7]);
        // --- stage W: 256 rows, one row per thread (32 bf16 = 4x uint4) ---
        {
            const unsigned short* wp = W + (size_t)tid * KKANP + k0;
            uint4 w0 = ((const uint4*)wp)[0];
            uint4 w1 = ((const uint4*)wp)[1];
            uint4 w2 = ((const uint4*)wp)[2];
            uint4 w3 = ((const uint4*)wp)[3];
            unsigned short* wd = &Ws[tid*LDK];
            *(uint4*)(wd)      = w0;
            *(uint4*)(wd + 8)  = w1;
            *(uint4*)(wd + 16) = w2;
            *(uint4*)(wd + 24) = w3;
        }
        __syncthreads();
        bf16x8 af[4], bfr[8];
        #pragma unroll
        for (int mi = 0; mi < 4; ++mi)
            af[mi] = *reinterpret_cast<const bf16x8*>(&As[(wr*64 + mi*16 + r16)*LDK + g*8]);
        #pragma unroll
        for (int ni = 0; ni < 8; ++ni)
            bfr[ni] = *reinterpret_cast<const bf16x8*>(&Ws[(wc*128 + ni*16 + r16)*LDK + g*8]);
        #pragma unroll
        for (int mi = 0; mi < 4; ++mi)
            #pragma unroll
            for (int ni = 0; ni < 8; ++ni)
                acc[mi][ni] = __builtin_amdgcn_mfma_f32_16x16x32_bf16(
                    af[mi], bfr[ni], acc[mi][ni], 0, 0, 0);
        __syncthreads();
    }
    // --- epilogue: +bias, row LN stats, norm+relu, frame-mean, write cat ---
    float bias8[8], g8[8], b8[8];
    #pragma unroll
    for (int ni = 0; ni < 8; ++ni) {
        int col = wc*128 + ni*16 + r16;
        bias8[ni] = kbias[col]; g8[ni] = fng[col]; b8[ni] = fnb[col];
    }
    #pragma unroll
    for (int mi = 0; mi < 4; ++mi) {
        #pragma unroll
        for (int j = 0; j < 4; ++j) {
            float s = 0.f, q = 0.f;
            #pragma unroll
            for (int ni = 0; ni < 8; ++ni) {
                float v = acc[mi][ni][j] + bias8[ni];
                s += v; q += v*v;
            }
            #pragma unroll
            for (int off = 1; off < 16; off <<= 1) {
                s += __shfl_xor(s, off);
                q += __shfl_xor(q, off);
            }
            if (r16 == 0) {
                int row = wr*64 + mi*16 + g*4 + j;
                rsum[row][wc] = s; rsq[row][wc] = q;
            }
        }
    }
    __syncthreads();
    #pragma unroll
    for (int mi = 0; mi < 4; ++mi) {
        int row0 = wr*64 + mi*16 + g*4;
        float o8[8] = {0.f,0.f,0.f,0.f,0.f,0.f,0.f,0.f};
        #pragma unroll
        for (int j = 0; j < 4; ++j) {
            int row = row0 + j;
            float sm = rsum[row][0] + rsum[row][1];
            float sq = rsq[row][0] + rsq[row][1];
            float mn = sm * (1.f/256.f);
            float var = fmaxf(sq * (1.f/256.f) - mn*mn, 0.f);  // clamp: no cancellation NaN
            float rstd = rsqrtf(var + 1e-5f);
            #pragma unroll
            for (int ni = 0; ni < 8; ++ni) {
                float v = acc[mi][ni][j] + bias8[ni];
                v = (v - mn) * rstd * g8[ni] + b8[ni];
                o8[ni] += fmaxf(v, 0.f);
            }
        }
        int rbl = (bm + row0) >> 2;
        float* crow = cat + (size_t)rbl * CATD;
        #pragma unroll
        for (int ni = 0; ni < 8; ++ni)
            crow[wc*128 + ni*16 + r16] = o8[ni] * 0.25f;
    }
}

// ---------------- generic f32 GEMM (tiny N only) ----------------
__global__ __launch_bounds__(256) void gemm_f32(
    const float* __restrict__ A, const float* __restrict__ W,
    const float* __restrict__ bias, float* __restrict__ C,
    int N, int K, int lda, int ldc, int act, int accum)
{
    __shared__ float As[16][68];
    __shared__ float Ws[16][68];
    const int tid = threadIdx.x;
    const int bm = blockIdx.x * 64;
    const int bn = blockIdx.y * 64;
    const int ty = tid >> 4, tx = tid & 15;
    const int lr = tid >> 2;
    const int lk = (tid & 3) * 4;
    float acc[4][4] = {{0.f,0.f,0.f,0.f},{0.f,0.f,0.f,0.f},{0.f,0.f,0.f,0.f},{0.f,0.f,0.f,0.f}};

    for (int k0 = 0; k0 < K; k0 += 16) {
        float4 av = *reinterpret_cast<const float4*>(A + (size_t)(bm + lr) * lda + k0 + lk);
        As[lk+0][lr] = av.x; As[lk+1][lr] = av.y; As[lk+2][lr] = av.z; As[lk+3][lr] = av.w;
        float4 wv = make_float4(0.f, 0.f, 0.f, 0.f);
        if (bn + lr < N)
            wv = *reinterpret_cast<const float4*>(W + (size_t)(bn + lr) * K + k0 + lk);
        Ws[lk+0][lr] = wv.x; Ws[lk+1][lr] = wv.y; Ws[lk+2][lr] = wv.z; Ws[lk+3][lr] = wv.w;
        __syncthreads();
        #pragma unroll
        for (int kk = 0; kk < 16; ++kk) {
            float4 a4 = *reinterpret_cast<const float4*>(&As[kk][ty*4]);
            float4 b4 = *reinterpret_cast<const float4*>(&Ws[kk][tx*4]);
            float aa[4] = {a4.x, a4.y, a4.z, a4.w};
            float bb[4] = {b4.x, b4.y, b4.z, b4.w};
            #pragma unroll
            for (int i = 0; i < 4; ++i)
                #pragma unroll
                for (int j = 0; j < 4; ++j)
                    acc[i][j] = fmaf(aa[i], bb[j], acc[i][j]);
        }
        __syncthreads();
    }
    #pragma unroll
    for (int i = 0; i < 4; ++i) {
        int row = bm + ty*4 + i;
        #pragma unroll
        for (int j = 0; j < 4; ++j) {
            int col = bn + tx*4 + j;
            if (col < N) {
                float v = acc[i][j];
                if (bias) v += bias[col];
                if (act == 1) v = fmaxf(v, 0.f);
                else if (act == 2) v = fmaxf(v, 0.f) + log1pf(expf(-fabsf(v)));
                size_t o = (size_t)row * ldc + col;
                if (accum) v += C[o];
                C[o] = v;
            }
        }
    }
}

// ---------------- prep kernels ----------------
__global__ void prep_bf16(const float* __restrict__ src, unsigned short* __restrict__ dst,
                          int N, int K, int Kp)
{
    int idx = blockIdx.x * 256 + threadIdx.x;
    if (idx >= N * Kp) return;
    int n = idx / Kp, k = idx - n * Kp;
    dst[idx] = (k < K) ? f2bf(src[(size_t)n * K + k]) : (unsigned short)0;
}

__global__ void prep_waug16(const float* __restrict__ sp, const float* __restrict__ sc,
                            unsigned short* __restrict__ Wg)
{
    int idx = blockIdx.x * 256 + threadIdx.x;
    if (idx >= DM * KKANP) return;
    int o = idx >> 8, k = idx & 255;
    float v = 0.f;
    if (k < KREALK) {
        int i = k >> 1;
        if (k & 1) {
            const float* s5 = sp + ((size_t)o*FD + i)*5;
            v = s5[0] + s5[1] + s5[2] + s5[3] + s5[4];
        } else v = sc[o*FD + i];
    }
    Wg[idx] = f2bf(v);
}

__global__ void prep_wbc(const float* __restrict__ WB, const float* __restrict__ WC,
                         float* __restrict__ Wg)
{
    int idx = blockIdx.x * 256 + threadIdx.x;
    if (idx >= 32 * DM) return;
    int n = idx >> 8, k = idx & 255;
    Wg[idx] = (n < 16) ? WB[n*DM + k] : WC[(n-16)*DM + k];
}

// ---------------- KAN per-row LN stats ----------------
__global__ __launch_bounds__(256) void kan_stats(const float* __restrict__ obs,
                                                 float* __restrict__ stats)
{
    int row = blockIdx.x * 4 + (threadIdx.x >> 6);
    int lane = threadIdx.x & 63;
    const float* o = obs + (size_t)row * FD;
    float v0 = o[lane];
    float v1 = (lane + 64 < FD) ? o[lane + 64] : 0.f;
    float s = v0 + v1;
    for (int off = 32; off; off >>= 1) s += __shfl_xor(s, off);
    float m = s * (1.f / FD);
    float e0 = v0 - m;
    float e1 = (lane + 64 < FD) ? (v1 - m) : 0.f;
    float ss = e0*e0 + e1*e1;
    for (int off = 32; off; off >>= 1) ss += __shfl_xor(ss, off);
    if (lane == 0) {
        stats[2*row]   = m;
        stats[2*row+1] = rsqrtf(ss * (1.f / FD) + 1e-5f);
    }
}

// ---------------- graph feature -> cat[256:288] ----------------
__global__ __launch_bounds__(64) void graph_kernel(const float* __restrict__ obs,
    const float* __restrict__ gW, const float* __restrict__ ewp,
    float* __restrict__ out)
{
    __shared__ float px[NP], py[NP];
    __shared__ float nodes[NP][8];
    __shared__ float gxs[NP][GH];
    __shared__ unsigned int msk[NP];
    __shared__ float rden[NP];
    __shared__ float wgt[NP];
    const int row = blockIdx.x;
    const int lane = threadIdx.x;
    const float* fc = obs + ((size_t)row * NF + 3) * FD;
    const float* fp = obs + ((size_t)row * NF + 2) * FD;
    const float ew = ewp[0];

    if (lane < NP) {
        int i = lane;
        float p0, p1, q0, q1;
        if (i < 11) { p0 = fc[3+2*i];  p1 = fc[4+2*i];  q0 = fp[3+2*i];  q1 = fp[4+2*i]; }
        else { int ii = i-11; p0 = fc[25+2*ii]; p1 = fc[26+2*ii]; q0 = fp[25+2*ii]; q1 = fp[26+2*ii]; }
        px[i] = p0; py[i] = p1;
        float bx = fc[0], by = fc[1];
        float bd = sqrtf((p0-bx)*(p0-bx) + (p1-by)*(p1-by));
        nodes[i][0] = p0; nodes[i][1] = p1;
        nodes[i][2] = p0 - q0; nodes[i][3] = p1 - q1;
        nodes[i][4] = (i < 11) ? 0.f : 1.f;
        nodes[i][5] = expf(-2.f * bd);
    }
    __syncthreads();
    if (lane < NP) {
        int base = (lane < 11) ? 0 : 11;
        float cx = 0.f, cy = 0.f;
        for (int j = 0; j < 11; ++j) { cx += px[base+j]; cy += py[base+j]; }
        cx *= (1.f/11.f); cy *= (1.f/11.f);
        nodes[lane][6] = px[lane] - cx;
        nodes[lane][7] = py[lane] - cy;
        unsigned sel = 0;
        for (int k = 0; k < GKN; ++k) {
            float best = 1e30f; int bj = 0;
            for (int j = 0; j < NP; ++j) {
                if (j == lane || ((sel >> j) & 1u)) continue;
                float dx = px[lane]-px[j], dy = py[lane]-py[j];
                float dd = sqrtf(dx*dx + dy*dy);
                if (dd < best) { best = dd; bj = j; }
            }
            sel |= (1u << bj);
        }
        unsigned full = sel | (1u << lane);
        msk[lane] = full;
        rden[lane] = 1.f / fmaxf((float)__popc(full), 1.f);
    }
    __syncthreads();
    for (int idx = lane; idx < NP*GH; idx += 64) {
        int i = idx >> 5, h = idx & 31;
        float s = 0.f;
        #pragma unroll
        for (int f = 0; f < 8; ++f) s += nodes[i][f] * gW[h*8 + f];
        gxs[i][h] = s;
    }
    __syncthreads();
    if (lane < NP) {
        float s = 0.f;
        for (int i = 0; i < NP; ++i) if ((msk[i] >> lane) & 1u) s += rden[i];
        wgt[lane] = (1.f - ew) + ew * s;
    }
    __syncthreads();
    if (lane < GH) {
        float s = 0.f;
        for (int j = 0; j < NP; ++j) s += wgt[j] * gxs[j][lane];
        out[(size_t)row * CATD + DM + lane] = s * (1.f/22.f);
    }
}

// ---------------- action embedding gather -> cat[288:304] ----------------
__global__ void gather_aemb(const int* __restrict__ pa, const float* __restrict__ emb,
                            float* __restrict__ out)
{
    int idx = blockIdx.x * 256 + threadIdx.x;
    int row = idx >> 4, e = idx & 15;
    out[(size_t)row * CATD + DM + GH + e] = emb[pa[row]*AEM + e];
}

// ---------------- LN over 256 cols ----------------
__global__ __launch_bounds__(256) void ln256(const float* __restrict__ X,
    const float* __restrict__ g, const float* __restrict__ b, float* __restrict__ Y)
{
    int row = blockIdx.x * 4 + (threadIdx.x >> 6);
    int lane = threadIdx.x & 63;
    const float* x = X + (size_t)row * DM;
    float4 v = reinterpret_cast<const float4*>(x)[lane];
    float s = v.x + v.y + v.z + v.w;
    for (int off = 32; off; off >>= 1) s += __shfl_xor(s, off);
    float m = s * (1.f / DM);
    float d0 = v.x-m, d1 = v.y-m, d2 = v.z-m, d3 = v.w-m;
    float ss = d0*d0 + d1*d1 + d2*d2 + d3*d3;
    for (int off = 32; off; off >>= 1) ss += __shfl_xor(ss, off);
    float rstd = rsqrtf(ss * (1.f / DM) + 1e-5f);
    int c = lane * 4;
    float4 o4 = make_float4(d0*rstd*g[c+0] + b[c+0],
                            d1*rstd*g[c+1] + b[c+1],
                            d2*rstd*g[c+2] + b[c+2],
                            d3*rstd*g[c+3] + b[c+3]);
    reinterpret_cast<float4*>(Y + (size_t)row * DM)[lane] = o4;
}

// ======== S6 chunked parallel scan ========
__global__ __launch_bounds__(256) void s6_chunkA(
    const float* __restrict__ dt, const float* __restrict__ xz,
    const float* __restrict__ bc, const float* __restrict__ Alog,
    float* __restrict__ P, float* __restrict__ S)
{
    const int blk = blockIdx.x;
    const int dblk = blk & 15, c = (blk >> 4) & 7, b = blk >> 7;
    const int s = threadIdx.x & 15, dl = threadIdx.x >> 4;
    const int d = dblk*16 + dl;
    const float A = -expf(Alog[d*DS + s]);
    const size_t r0 = (size_t)b*LL + c*CL;
    float Pv = 1.f, Sv = 0.f;
    for (int t = 0; t < CL; ++t) {
        size_t r = r0 + t;
        float dtv = dt[r*DM + d];
        float xv  = xz[r*512 + d];
        float Bv  = bc[r*32 + s];
        float dA  = expf(dtv * A);
        Pv *= dA;
        Sv = fmaf(dA, Sv, dtv * xv * Bv);
    }
    size_t o = (((size_t)b*NC + c)*DM + d)*DS + s;
    P[o] = Pv; S[o] = Sv;
}

__global__ __launch_bounds__(256) void s6_comb(
    const float* __restrict__ P, const float* __restrict__ S,
    const float* __restrict__ h0, float* __restrict__ hin, float* __restrict__ hout)
{
    int idx = blockIdx.x * 256 + threadIdx.x;
    int b = idx >> 12, ds = idx & 4095;
    float h = h0[idx];
    #pragma unroll
    for (int c = 0; c < NC; ++c) {
        size_t o = (((size_t)b*NC + c) << 12) + ds;
        hin[o] = h;
        h = fmaf(P[o], h, S[o]);
    }
    hout[idx] = h;
}

__global__ __launch_bounds__(256) void s6_chunkC(
    const float* __restrict__ dt, const float* __restrict__ xz,
    const float* __restrict__ bc, const float* __restrict__ Alog,
    const float* __restrict__ hin, const float* __restrict__ Dp,
    float* __restrict__ ssm)
{
    const int blk = blockIdx.x;
    const int dblk = blk & 15, c = (blk >> 4) & 7, b = blk >> 7;
    const int s = threadIdx.x & 15, dl = threadIdx.x >> 4;
    const int d = dblk*16 + dl;
    const float A = -expf(Alog[d*DS + s]);
    const float Dv = Dp[d];
    const size_t r0 = (size_t)b*LL + c*CL;
    float h = hin[(((size_t)b*NC + c)*DM + d)*DS + s];
    for (int t = 0; t < CL; ++t) {
        size_t r = r0 + t;
        float dtv = dt[r*DM + d];   // read before same-wave store to same addr
        float xv  = xz[r*512 + d];
        float Bv  = bc[r*32 + s];
        float Cv  = bc[r*32 + 16 + s];
        float dA  = expf(dtv * A);
        h = fmaf(dA, h, dtv * xv * Bv);
        float p = h * Cv;
        p += __shfl_xor(p, 1);
        p += __shfl_xor(p, 2);
        p += __shfl_xor(p, 4);
        p += __shfl_xor(p, 8);
        if (s == 0) {
            float zv = xz[r*512 + 256 + d];
            float sil = zv / (1.f + expf(-zv));
            ssm[r*DM + d] = fmaf(p, sil, xv * Dv);
        }
    }
}

// ---------------- host ----------------
static inline void mgemm(hipStream_t st, const float* A, const unsigned short* W,
                         const float* bias, float* C, int M, int N, int Kp, int Kreal,
                         int lda, int ldc, int act, int accum) {
    dim3 g(M/128, (N+127)/128);
    mfma_gemm<<<g, 256, 0, st>>>(A, W, bias, C, N, Kp, Kreal, lda, ldc, act, accum);
}
static inline void gemm(hipStream_t st, const float* A, const float* W, const float* bias,
                        float* C, int M, int N, int K, int lda, int ldc, int act, int accum) {
    dim3 g(M/64, (N+63)/64);
    gemm_f32<<<g, 256, 0, st>>>(A, W, bias, C, N, K, lda, ldc, act, accum);
}

extern "C" void kernel_launch(void* const* d_in, const int* in_sizes, int n_in,
                              void* d_out, int out_size, void* d_ws, size_t ws_size,
                              hipStream_t stream) {
    (void)in_sizes; (void)n_in; (void)out_size; (void)ws_size;
    const float* obs      = (const float*)d_in[0];
    const int*   pa       = (const int*)d_in[1];
    const float* h0in[2]  = {(const float*)d_in[2], (const float*)d_in[3]};
    const float* kan_ln_g = (const float*)d_in[4];
    const float* kan_ln_b = (const float*)d_in[5];
    const float* kan_sp   = (const float*)d_in[6];
    const float* kan_sc   = (const float*)d_in[7];
    const float* kan_bias = (const float*)d_in[8];
    const float* kan_beta = (const float*)d_in[9];
    const float* fn_g     = (const float*)d_in[10];
    const float* fn_b     = (const float*)d_in[11];
    const float* gnn_W    = (const float*)d_in[12];
    const float* edge_w   = (const float*)d_in[13];
    const float* act_emb  = (const float*)d_in[14];
    const float* W_ip     = (const float*)d_in[15];
    const float* b_ip     = (const float*)d_in[16];
    const float* fl_g     = (const float*)d_in[37];
    const float* fl_b     = (const float*)d_in[38];
    const float* pW1      = (const float*)d_in[39];
    const float* pb1      = (const float*)d_in[40];
    const float* pW2      = (const float*)d_in[41];
    const float* pb2      = (const float*)d_in[42];
    const float* vW1      = (const float*)d_in[43];
    const float* vb1      = (const float*)d_in[44];
    const float* vW2      = (const float*)d_in[45];
    const float* vb2      = (const float*)d_in[46];

    // --- workspace arena (floats). Peak = 26,476,544 fl <= round-3's proven footprint.
    const size_t SZ_BIG = (size_t)BLR * DM;           // 4,194,304
    float* ws = (float*)d_ws;
    float* X  = ws;                                   // residual
    float* R0 = X  + SZ_BIG;                          // xn
    float* R1 = R0 + SZ_BIG;                          // XZ lo (R2 = XZ hi implicit)
    float* R3 = R1 + 2*SZ_BIG;                        // dt -> ssm
    float* R4 = R3 + SZ_BIG;                          // cat BLRxCATD; later overlays
    float* R5 = R4 + (size_t)BLR * CATD;              // BC BLRx32; earlier WIP/WAUG/STATS
    // R5 overlays (dead once BC is first written in layer 0):
    unsigned short* WIP16  = (unsigned short*)R5;                 // 256x320 bf16
    unsigned short* WAUG16 = WIP16 + (size_t)DM*CATP;             // 256x256 bf16
    float*          STATS  = R5 + 40960 + 32768;                  // 65536x2 f32
    // R4 overlays (dead once input projection consumed cat):
    const size_t CH = (size_t)BB * NC * DM * DS;      // 524,288
    float* Pbuf = R4;
    float* Sbuf = R4 + CH;
    float* HIN  = R4 + 2*CH;
    unsigned short* WIN16  = (unsigned short*)(R4 + 3*CH);        // 512x256
    unsigned short* WDT16  = WIN16 + 512*DM;                      // 256x256
    unsigned short* WOUT16 = WDT16 + DM*DM;                       // 256x256
    unsigned short* PW116  = WOUT16 + DM*DM;                      // 128x256
    unsigned short* VW116  = PW116 + 128*DM;                      // 64x256
    float* WBC = (float*)(VW116 + 64*DM);                         // 32x256 f32

    float* XZ = R1;                                   // BLR x 512

    float* out        = (float*)d_out;
    float* out_logits = out;
    float* out_value  = out + (size_t)BLR * NACTN;
    float* out_h[2]   = {out + (size_t)BLR*NACTN + BLR,
                         out + (size_t)BLR*NACTN + BLR + (size_t)BB*DM*DS};

    // --- KAN phase (WIP16/WAUG16/STATS live in R5) ---
    prep_waug16<<<(DM*KKANP+255)/256, 256, 0, stream>>>(kan_sp, kan_sc, WAUG16);
    prep_bf16<<<(DM*CATP+255)/256, 256, 0, stream>>>(W_ip, WIP16, DM, CATD, CATP);
    kan_stats<<<BLR*NF/4, 256, 0, stream>>>(obs, STATS);
    kan_fused<<<BLR*NF/128, 256, 0, stream>>>(
        obs, STATS, kan_ln_g, kan_ln_b, kan_beta, WAUG16, kan_bias, fn_g, fn_b, R4);
    graph_kernel<<<BLR, 64, 0, stream>>>(obs, gnn_W, edge_w, R4);
    gather_aemb<<<BLR*AEM/256, 256, 0, stream>>>(pa, act_emb, R4);

    // --- input projection: K=304 real, Kp=320 (weight zero-pad + Kreal guard) ---
    mgemm(stream, R4, WIP16, b_ip, X, BLR, DM, CATP, CATD, CATD, DM, 0, 0);

    // --- head weight preps (cat now dead; R4 overlay) ---
    prep_bf16<<<(128*DM+255)/256, 256, 0, stream>>>(pW1, PW116, 128, DM, DM);
    prep_bf16<<<(64*DM+255)/256, 256, 0, stream>>>(vW1, VW116, 64, DM, DM);

    // --- two S6 layers ---
    for (int l = 0; l < 2; ++l) {
        const float* lng  = (const float*)d_in[17 + 10*l + 0];
        const float* lnb  = (const float*)d_in[17 + 10*l + 1];
        const float* Win  = (const float*)d_in[17 + 10*l + 2];
        const float* Wdt  = (const float*)d_in[17 + 10*l + 3];
        const float* bdt  = (const float*)d_in[17 + 10*l + 4];
        const float* Alog = (const float*)d_in[17 + 10*l + 5];
        const float* WBp  = (const float*)d_in[17 + 10*l + 6];
        const float* WCp  = (const float*)d_in[17 + 10*l + 7];
        const float* Dp   = (const float*)d_in[17 + 10*l + 8];
        const float* Wout = (const float*)d_in[17 + 10*l + 9];

        prep_bf16<<<(512*DM+255)/256, 256, 0, stream>>>(Win, WIN16, 512, DM, DM);
        prep_bf16<<<(DM*DM+255)/256, 256, 0, stream>>>(Wdt, WDT16, DM, DM, DM);
        prep_bf16<<<(DM*DM+255)/256, 256, 0, stream>>>(Wout, WOUT16, DM, DM, DM);
        prep_wbc<<<32, 256, 0, stream>>>(WBp, WCp, WBC);

        ln256<<<BLR/4, 256, 0, stream>>>(X, lng, lnb, R0);
        mgemm(stream, R0, WIN16, nullptr, XZ, BLR, 512, DM, DM, DM, 512, 0, 0);
        mgemm(stream, XZ, WDT16, bdt, R3, BLR, DM, DM, DM, 512, DM, 2, 0);
        gemm(stream, XZ, WBC, nullptr, R5, BLR, 32, DM, 512, 32, 0, 0);
        s6_chunkA<<<BB*NC*16, 256, 0, stream>>>(R3, XZ, R5, Alog, Pbuf, Sbuf);
        s6_comb<<<BB*DM*DS/256, 256, 0, stream>>>(Pbuf, Sbuf, h0in[l], HIN, out_h[l]);
        s6_chunkC<<<BB*NC*16, 256, 0, stream>>>(R3, XZ, R5, Alog, HIN, Dp, R3);
        mgemm(stream, R3, WOUT16, nullptr, X, BLR, DM, DM, DM, DM, DM, 0, 1);
    }

    // --- heads ---
    ln256<<<BLR/4, 256, 0, stream>>>(X, fl_g, fl_b, R0);
    mgemm(stream, R0, PW116, pb1, R1, BLR, 128, DM, DM, DM, 128, 1, 0);
    gemm(stream, R1, pW2, pb2, out_logits, BLR, NACTN, 128, 128, NACTN, 0, 0);
    mgemm(stream, R0, VW116, vb1, R1 + (size_t)BLR*128, BLR, 64, DM, DM, DM, 64, 1, 0);
    gemm(stream, R1 + (size_t)BLR*128, vW2, vb2, out_value, BLR, 1, 64, 64, 1, 0, 0);
}

// Round 8
// 729.145 us; speedup vs baseline: 2.3110x; 1.1323x over previous
//
#include <hip/hip_runtime.h>
#include <math.h>

// ---------------- problem constants ----------------
#define BB   16
#define LL   1024
#define BLR  (BB*LL)        // 16384 rows
#define DM   256
#define DS   16
#define FD   115
#define NF   4
#define NACTN 19
#define GH   32
#define GKN  6
#define AEM  16
#define NP   22
#define CATD 304            // cat width (16-aligned, NOT padded)
#define CATP 320            // MFMA Kp for input proj
#define KKANP 256           // KAN K padded to x32
#define KREALK 230          // 115 inputs x {ln_x, sum_basis}
#define NC   8              // scan chunks
#define CL   (LL/NC)        // 128 steps per chunk
#define LDK  40             // LDS row stride in bf16 elems
#define XZW  544            // x_in(256) | z(256) | B(16) | C(16)

// NOTE on the KAN: the reference einsum 'big,oid->bo' has MISMATCHED grid
// subscripts (g vs d) -> contraction over i only with (sum_g basis)*(sum_d Wsp).
// NOTE on B/C: Bt = x_in @ WB^T (NOT xn @ WB^T) -- must be computed from the
// x_in columns of XZBC after the Win GEMM (round-7 bug: folded WB against xn).

typedef __attribute__((ext_vector_type(8))) short bf16x8;
typedef __attribute__((ext_vector_type(4))) float f32x4;

__device__ inline unsigned short f2bf(float f) {
    unsigned int u = __float_as_uint(f);
    u += 0x7fff + ((u >> 16) & 1);
    return (unsigned short)(u >> 16);
}
__device__ inline unsigned int f2bf2(float lo, float hi) {
    return (unsigned int)f2bf(lo) | ((unsigned int)f2bf(hi) << 16);
}

// ============ MFMA GEMM: C[M,N] = act(A_f32[M,Kreal] @ W_bf16[N,Kp]^T + bias) (+C) ==
__global__ __launch_bounds__(256) void mfma_gemm(
    const float* __restrict__ A, const unsigned short* __restrict__ W,
    const float* __restrict__ bias, float* __restrict__ C,
    int N, int Kp, int Kreal, int lda, int ldc, int act, int accum)
{
    __shared__ __align__(16) unsigned short As[128*LDK];
    __shared__ __align__(16) unsigned short Ws[128*LDK];
    const int tid = threadIdx.x;
    const int bm = blockIdx.x * 128;
    const int bn = blockIdx.y * 128;
    const int wid = tid >> 6, lane = tid & 63;
    const int wr = wid >> 1, wc = wid & 1;
    const int g = lane >> 4, r16 = lane & 15;
    const int srow = tid >> 1;            // 0..127
    const int shalf = (tid & 1) * 16;     // k offset 0/16

    f32x4 acc[4][4] = {};
    for (int k0 = 0; k0 < Kp; k0 += 32) {
        uint4 alo = make_uint4(0u,0u,0u,0u), ahi = make_uint4(0u,0u,0u,0u);
        if (k0 + shalf < Kreal) {
            const float* ap = A + (size_t)(bm + srow) * lda + k0 + shalf;
            float4 a0 = *(const float4*)(ap);
            float4 a1 = *(const float4*)(ap + 4);
            float4 a2 = *(const float4*)(ap + 8);
            float4 a3 = *(const float4*)(ap + 12);
            alo = make_uint4(f2bf2(a0.x,a0.y), f2bf2(a0.z,a0.w),
                             f2bf2(a1.x,a1.y), f2bf2(a1.z,a1.w));
            ahi = make_uint4(f2bf2(a2.x,a2.y), f2bf2(a2.z,a2.w),
                             f2bf2(a3.x,a3.y), f2bf2(a3.z,a3.w));
        }
        unsigned short* ad = &As[srow*LDK + shalf];
        *(uint4*)(ad)     = alo;
        *(uint4*)(ad + 8) = ahi;
        int n = bn + srow;
        uint4 wv0 = make_uint4(0u,0u,0u,0u), wv1 = make_uint4(0u,0u,0u,0u);
        if (n < N) {
            const unsigned short* wp = W + (size_t)n * Kp + k0 + shalf;
            wv0 = ((const uint4*)wp)[0];
            wv1 = ((const uint4*)wp)[1];
        }
        unsigned short* wd = &Ws[srow*LDK + shalf];
        *(uint4*)(wd)     = wv0;
        *(uint4*)(wd + 8) = wv1;
        __syncthreads();

        bf16x8 af[4], bfr[4];
        #pragma unroll
        for (int mi = 0; mi < 4; ++mi)
            af[mi] = *reinterpret_cast<const bf16x8*>(&As[(wr*64 + mi*16 + r16)*LDK + g*8]);
        #pragma unroll
        for (int ni = 0; ni < 4; ++ni)
            bfr[ni] = *reinterpret_cast<const bf16x8*>(&Ws[(wc*64 + ni*16 + r16)*LDK + g*8]);
        #pragma unroll
        for (int mi = 0; mi < 4; ++mi)
            #pragma unroll
            for (int ni = 0; ni < 4; ++ni)
                acc[mi][ni] = __builtin_amdgcn_mfma_f32_16x16x32_bf16(
                    af[mi], bfr[ni], acc[mi][ni], 0, 0, 0);
        __syncthreads();
    }
    #pragma unroll
    for (int mi = 0; mi < 4; ++mi) {
        #pragma unroll
        for (int j = 0; j < 4; ++j) {
            int row = bm + wr*64 + mi*16 + g*4 + j;
            float* crow = C + (size_t)row * ldc;
            #pragma unroll
            for (int ni = 0; ni < 4; ++ni) {
                int col = bn + wc*64 + ni*16 + r16;
                if (col < N) {
                    float v = acc[mi][ni][j];
                    if (bias) v += bias[col];
                    if (act == 1) v = fmaxf(v, 0.f);
                    else if (act == 2) v = fmaxf(v, 0.f) + __logf(1.f + __expf(-fabsf(v)));
                    if (accum) v += crow[col];
                    crow[col] = v;
                }
            }
        }
    }
}

// ============ fused KAN: MFMA(gen(A), WAUG) + bias -> LN(256) -> relu -> frame-mean ==
__global__ __launch_bounds__(256) void kan_fused(
    const float* __restrict__ obs, const float* __restrict__ stats,
    const float* __restrict__ lng, const float* __restrict__ lnb,
    const float* __restrict__ betap, const unsigned short* __restrict__ W,
    const float* __restrict__ kbias, const float* __restrict__ fng,
    const float* __restrict__ fnb, float* __restrict__ cat)
{
    __shared__ __align__(16) unsigned short As[128*LDK];
    __shared__ __align__(16) unsigned short Ws[256*LDK];
    __shared__ float rsum[128][2];
    __shared__ float rsq[128][2];
    const float beta = fminf(fmaxf(betap[0], 0.5f), 6.0f);
    const int tid = threadIdx.x;
    const int bm = blockIdx.x * 128;
    const int wid = tid >> 6, lane = tid & 63;
    const int wr = wid >> 1, wc = wid & 1;
    const int g = lane >> 4, r16 = lane & 15;
    const int srow = tid >> 1;
    const int shalf = (tid & 1) * 16;
    const int r = bm + srow;
    const float m  = stats[2*r];
    const float rs = stats[2*r+1];
    const float* orow = obs + (size_t)r * FD;

    f32x4 acc[4][8] = {};
    for (int k0 = 0; k0 < KKANP; k0 += 32) {
        int i0 = (k0 + shalf) >> 1;
        unsigned int pk[8];
        #pragma unroll
        for (int q = 0; q < 8; ++q) {
            int i = i0 + q;
            float xv = 0.f, sb = 0.f;
            if (i < FD) {
                float x = (orow[i] - m) * rs * lng[i] + lnb[i];
                xv = x;
                #pragma unroll
                for (int g5 = 0; g5 < 5; ++g5) {
                    float dx = x - (-1.f + 0.5f * (float)g5);
                    sb += __expf(-dx*dx*beta);
                }
            }
            pk[q] = f2bf2(xv, sb);
        }
        unsigned short* ad = &As[srow*LDK + shalf];
        *(uint4*)(ad)     = make_uint4(pk[0], pk[1], pk[2], pk[3]);
        *(uint4*)(ad + 8) = make_uint4(pk[4], pk[5], pk[6], pk[7]);
        {
            const unsigned short* wp = W + (size_t)tid * KKANP + k0;
            uint4 w0 = ((const uint4*)wp)[0];
            uint4 w1 = ((const uint4*)wp)[1];
            uint4 w2 = ((const uint4*)wp)[2];
            uint4 w3 = ((const uint4*)wp)[3];
            unsigned short* wd = &Ws[tid*LDK];
            *(uint4*)(wd)      = w0;
            *(uint4*)(wd + 8)  = w1;
            *(uint4*)(wd + 16) = w2;
            *(uint4*)(wd + 24) = w3;
        }
        __syncthreads();
        bf16x8 af[4], bfr[8];
        #pragma unroll
        for (int mi = 0; mi < 4; ++mi)
            af[mi] = *reinterpret_cast<const bf16x8*>(&As[(wr*64 + mi*16 + r16)*LDK + g*8]);
        #pragma unroll
        for (int ni = 0; ni < 8; ++ni)
            bfr[ni] = *reinterpret_cast<const bf16x8*>(&Ws[(wc*128 + ni*16 + r16)*LDK + g*8]);
        #pragma unroll
        for (int mi = 0; mi < 4; ++mi)
            #pragma unroll
            for (int ni = 0; ni < 8; ++ni)
                acc[mi][ni] = __builtin_amdgcn_mfma_f32_16x16x32_bf16(
                    af[mi], bfr[ni], acc[mi][ni], 0, 0, 0);
        __syncthreads();
    }
    float bias8[8], g8[8], b8[8];
    #pragma unroll
    for (int ni = 0; ni < 8; ++ni) {
        int col = wc*128 + ni*16 + r16;
        bias8[ni] = kbias[col]; g8[ni] = fng[col]; b8[ni] = fnb[col];
    }
    #pragma unroll
    for (int mi = 0; mi < 4; ++mi) {
        #pragma unroll
        for (int j = 0; j < 4; ++j) {
            float s = 0.f, q = 0.f;
            #pragma unroll
            for (int ni = 0; ni < 8; ++ni) {
                float v = acc[mi][ni][j] + bias8[ni];
                s += v; q += v*v;
            }
            #pragma unroll
            for (int off = 1; off < 16; off <<= 1) {
                s += __shfl_xor(s, off);
                q += __shfl_xor(q, off);
            }
            if (r16 == 0) {
                int row = wr*64 + mi*16 + g*4 + j;
                rsum[row][wc] = s; rsq[row][wc] = q;
            }
        }
    }
    __syncthreads();
    #pragma unroll
    for (int mi = 0; mi < 4; ++mi) {
        int row0 = wr*64 + mi*16 + g*4;
        float o8[8] = {0.f,0.f,0.f,0.f,0.f,0.f,0.f,0.f};
        #pragma unroll
        for (int j = 0; j < 4; ++j) {
            int row = row0 + j;
            float sm = rsum[row][0] + rsum[row][1];
            float sq = rsq[row][0] + rsq[row][1];
            float mn = sm * (1.f/256.f);
            float var = fmaxf(sq * (1.f/256.f) - mn*mn, 0.f);
            float rstd = rsqrtf(var + 1e-5f);
            #pragma unroll
            for (int ni = 0; ni < 8; ++ni) {
                float v = acc[mi][ni][j] + bias8[ni];
                v = (v - mn) * rstd * g8[ni] + b8[ni];
                o8[ni] += fmaxf(v, 0.f);
            }
        }
        int rbl = (bm + row0) >> 2;
        float* crow = cat + (size_t)rbl * CATD;
        #pragma unroll
        for (int ni = 0; ni < 8; ++ni)
            crow[wc*128 + ni*16 + r16] = o8[ni] * 0.25f;
    }
}

// ---------------- generic f32 GEMM (tiny N: BC + heads) ----------------
__global__ __launch_bounds__(256) void gemm_f32(
    const float* __restrict__ A, const float* __restrict__ W,
    const float* __restrict__ bias, float* __restrict__ C,
    int N, int K, int lda, int ldc, int act, int accum)
{
    __shared__ float As[16][68];
    __shared__ float Ws[16][68];
    const int tid = threadIdx.x;
    const int bm = blockIdx.x * 64;
    const int bn = blockIdx.y * 64;
    const int ty = tid >> 4, tx = tid & 15;
    const int lr = tid >> 2;
    const int lk = (tid & 3) * 4;
    float acc[4][4] = {{0.f,0.f,0.f,0.f},{0.f,0.f,0.f,0.f},{0.f,0.f,0.f,0.f},{0.f,0.f,0.f,0.f}};

    for (int k0 = 0; k0 < K; k0 += 16) {
        float4 av = *reinterpret_cast<const float4*>(A + (size_t)(bm + lr) * lda + k0 + lk);
        As[lk+0][lr] = av.x; As[lk+1][lr] = av.y; As[lk+2][lr] = av.z; As[lk+3][lr] = av.w;
        float4 wv = make_float4(0.f, 0.f, 0.f, 0.f);
        if (bn + lr < N)
            wv = *reinterpret_cast<const float4*>(W + (size_t)(bn + lr) * K + k0 + lk);
        Ws[lk+0][lr] = wv.x; Ws[lk+1][lr] = wv.y; Ws[lk+2][lr] = wv.z; Ws[lk+3][lr] = wv.w;
        __syncthreads();
        #pragma unroll
        for (int kk = 0; kk < 16; ++kk) {
            float4 a4 = *reinterpret_cast<const float4*>(&As[kk][ty*4]);
            float4 b4 = *reinterpret_cast<const float4*>(&Ws[kk][tx*4]);
            float aa[4] = {a4.x, a4.y, a4.z, a4.w};
            float bb[4] = {b4.x, b4.y, b4.z, b4.w};
            #pragma unroll
            for (int i = 0; i < 4; ++i)
                #pragma unroll
                for (int j = 0; j < 4; ++j)
                    acc[i][j] = fmaf(aa[i], bb[j], acc[i][j]);
        }
        __syncthreads();
    }
    #pragma unroll
    for (int i = 0; i < 4; ++i) {
        int row = bm + ty*4 + i;
        #pragma unroll
        for (int j = 0; j < 4; ++j) {
            int col = bn + tx*4 + j;
            if (col < N) {
                float v = acc[i][j];
                if (bias) v += bias[col];
                if (act == 1) v = fmaxf(v, 0.f);
                size_t o = (size_t)row * ldc + col;
                if (accum) v += C[o];
                C[o] = v;
            }
        }
    }
}

// ---------------- prep kernels ----------------
__global__ void prep_bf16(const float* __restrict__ src, unsigned short* __restrict__ dst,
                          int N, int K, int Kp)
{
    int idx = blockIdx.x * 256 + threadIdx.x;
    if (idx >= N * Kp) return;
    int n = idx / Kp, k = idx - n * Kp;
    dst[idx] = (k < K) ? f2bf(src[(size_t)n * K + k]) : (unsigned short)0;
}

__global__ void prep_waug16(const float* __restrict__ sp, const float* __restrict__ sc,
                            unsigned short* __restrict__ Wg)
{
    int idx = blockIdx.x * 256 + threadIdx.x;
    if (idx >= DM * KKANP) return;
    int o = idx >> 8, k = idx & 255;
    float v = 0.f;
    if (k < KREALK) {
        int i = k >> 1;
        if (k & 1) {
            const float* s5 = sp + ((size_t)o*FD + i)*5;
            v = s5[0] + s5[1] + s5[2] + s5[3] + s5[4];
        } else v = sc[o*FD + i];
    }
    Wg[idx] = f2bf(v);
}

__global__ void prep_wbc(const float* __restrict__ WB, const float* __restrict__ WC,
                         float* __restrict__ Wg)
{
    int idx = blockIdx.x * 256 + threadIdx.x;   // 32*256
    if (idx >= 32 * DM) return;
    int n = idx >> 8, k = idx & 255;
    Wg[idx] = (n < 16) ? WB[n*DM + k] : WC[(n-16)*DM + k];
}

// ---------------- KAN per-row LN stats ----------------
__global__ __launch_bounds__(256) void kan_stats(const float* __restrict__ obs,
                                                 float* __restrict__ stats)
{
    int row = blockIdx.x * 4 + (threadIdx.x >> 6);
    int lane = threadIdx.x & 63;
    const float* o = obs + (size_t)row * FD;
    float v0 = o[lane];
    float v1 = (lane + 64 < FD) ? o[lane + 64] : 0.f;
    float s = v0 + v1;
    for (int off = 32; off; off >>= 1) s += __shfl_xor(s, off);
    float m = s * (1.f / FD);
    float e0 = v0 - m;
    float e1 = (lane + 64 < FD) ? (v1 - m) : 0.f;
    float ss = e0*e0 + e1*e1;
    for (int off = 32; off; off >>= 1) ss += __shfl_xor(ss, off);
    if (lane == 0) {
        stats[2*row]   = m;
        stats[2*row+1] = rsqrtf(ss * (1.f / FD) + 1e-5f);
    }
}

// ---------------- graph feature -> cat[256:288] ----------------
__global__ __launch_bounds__(64) void graph_kernel(const float* __restrict__ obs,
    const float* __restrict__ gW, const float* __restrict__ ewp,
    float* __restrict__ out)
{
    __shared__ float px[NP], py[NP];
    __shared__ float nodes[NP][8];
    __shared__ float gxs[NP][GH];
    __shared__ unsigned int msk[NP];
    __shared__ float rden[NP];
    __shared__ float wgt[NP];
    const int row = blockIdx.x;
    const int lane = threadIdx.x;
    const float* fc = obs + ((size_t)row * NF + 3) * FD;
    const float* fp = obs + ((size_t)row * NF + 2) * FD;
    const float ew = ewp[0];

    if (lane < NP) {
        int i = lane;
        float p0, p1, q0, q1;
        if (i < 11) { p0 = fc[3+2*i];  p1 = fc[4+2*i];  q0 = fp[3+2*i];  q1 = fp[4+2*i]; }
        else { int ii = i-11; p0 = fc[25+2*ii]; p1 = fc[26+2*ii]; q0 = fp[25+2*ii]; q1 = fp[26+2*ii]; }
        px[i] = p0; py[i] = p1;
        float bx = fc[0], by = fc[1];
        float bd = sqrtf((p0-bx)*(p0-bx) + (p1-by)*(p1-by));
        nodes[i][0] = p0; nodes[i][1] = p1;
        nodes[i][2] = p0 - q0; nodes[i][3] = p1 - q1;
        nodes[i][4] = (i < 11) ? 0.f : 1.f;
        nodes[i][5] = __expf(-2.f * bd);
    }
    __syncthreads();
    if (lane < NP) {
        int base = (lane < 11) ? 0 : 11;
        float cx = 0.f, cy = 0.f;
        for (int j = 0; j < 11; ++j) { cx += px[base+j]; cy += py[base+j]; }
        cx *= (1.f/11.f); cy *= (1.f/11.f);
        nodes[lane][6] = px[lane] - cx;
        nodes[lane][7] = py[lane] - cy;
        unsigned sel = 0;
        for (int k = 0; k < GKN; ++k) {
            float best = 1e30f; int bj = 0;
            for (int j = 0; j < NP; ++j) {
                if (j == lane || ((sel >> j) & 1u)) continue;
                float dx = px[lane]-px[j], dy = py[lane]-py[j];
                float dd = sqrtf(dx*dx + dy*dy);
                if (dd < best) { best = dd; bj = j; }
            }
            sel |= (1u << bj);
        }
        unsigned full = sel | (1u << lane);
        msk[lane] = full;
        rden[lane] = 1.f / fmaxf((float)__popc(full), 1.f);
    }
    __syncthreads();
    for (int idx = lane; idx < NP*GH; idx += 64) {
        int i = idx >> 5, h = idx & 31;
        float s = 0.f;
        #pragma unroll
        for (int f = 0; f < 8; ++f) s += nodes[i][f] * gW[h*8 + f];
        gxs[i][h] = s;
    }
    __syncthreads();
    if (lane < NP) {
        float s = 0.f;
        for (int i = 0; i < NP; ++i) if ((msk[i] >> lane) & 1u) s += rden[i];
        wgt[lane] = (1.f - ew) + ew * s;
    }
    __syncthreads();
    if (lane < GH) {
        float s = 0.f;
        for (int j = 0; j < NP; ++j) s += wgt[j] * gxs[j][lane];
        out[(size_t)row * CATD + DM + lane] = s * (1.f/22.f);
    }
}

// ---------------- action embedding gather -> cat[288:304] ----------------
__global__ void gather_aemb(const int* __restrict__ pa, const float* __restrict__ emb,
                            float* __restrict__ out)
{
    int idx = blockIdx.x * 256 + threadIdx.x;
    int row = idx >> 4, e = idx & 15;
    out[(size_t)row * CATD + DM + GH + e] = emb[pa[row]*AEM + e];
}

// ---------------- LN over 256 cols ----------------
__global__ __launch_bounds__(256) void ln256(const float* __restrict__ X,
    const float* __restrict__ g, const float* __restrict__ b, float* __restrict__ Y)
{
    int row = blockIdx.x * 4 + (threadIdx.x >> 6);
    int lane = threadIdx.x & 63;
    const float* x = X + (size_t)row * DM;
    float4 v = reinterpret_cast<const float4*>(x)[lane];
    float s = v.x + v.y + v.z + v.w;
    for (int off = 32; off; off >>= 1) s += __shfl_xor(s, off);
    float m = s * (1.f / DM);
    float d0 = v.x-m, d1 = v.y-m, d2 = v.z-m, d3 = v.w-m;
    float ss = d0*d0 + d1*d1 + d2*d2 + d3*d3;
    for (int off = 32; off; off >>= 1) ss += __shfl_xor(ss, off);
    float rstd = rsqrtf(ss * (1.f / DM) + 1e-5f);
    int c = lane * 4;
    float4 o4 = make_float4(d0*rstd*g[c+0] + b[c+0],
                            d1*rstd*g[c+1] + b[c+1],
                            d2*rstd*g[c+2] + b[c+2],
                            d3*rstd*g[c+3] + b[c+3]);
    reinterpret_cast<float4*>(Y + (size_t)row * DM)[lane] = o4;
}

// ======== S6 chunked parallel scan (B,C in XZBC cols 512.., stride 544) ========
__global__ __launch_bounds__(256) void s6_chunkA(
    const float* __restrict__ dt, const float* __restrict__ xz,
    const float* __restrict__ Alog, float* __restrict__ P, float* __restrict__ S)
{
    const int blk = blockIdx.x;
    const int dblk = blk & 15, c = (blk >> 4) & 7, b = blk >> 7;
    const int s = threadIdx.x & 15, dl = threadIdx.x >> 4;
    const int d = dblk*16 + dl;
    const float A = -__expf(Alog[d*DS + s]);
    const size_t r0 = (size_t)b*LL + c*CL;
    float Pv = 1.f, Sv = 0.f;
    for (int t = 0; t < CL; ++t) {
        size_t r = r0 + t;
        float dtv = dt[r*DM + d];
        float xv  = xz[r*XZW + d];
        float Bv  = xz[r*XZW + 512 + s];
        float dA  = __expf(dtv * A);
        Pv *= dA;
        Sv = fmaf(dA, Sv, dtv * xv * Bv);
    }
    size_t o = (((size_t)b*NC + c)*DM + d)*DS + s;
    P[o] = Pv; S[o] = Sv;
}

__global__ __launch_bounds__(256) void s6_comb(
    const float* __restrict__ P, const float* __restrict__ S,
    const float* __restrict__ h0, float* __restrict__ hin, float* __restrict__ hout)
{
    int idx = blockIdx.x * 256 + threadIdx.x;
    int b = idx >> 12, ds = idx & 4095;
    float h = h0[idx];
    #pragma unroll
    for (int c = 0; c < NC; ++c) {
        size_t o = (((size_t)b*NC + c) << 12) + ds;
        hin[o] = h;
        h = fmaf(P[o], h, S[o]);
    }
    hout[idx] = h;
}

__global__ __launch_bounds__(256) void s6_chunkC(
    const float* __restrict__ dt, const float* __restrict__ xz,
    const float* __restrict__ Alog, const float* __restrict__ hin,
    const float* __restrict__ Dp, float* __restrict__ ssm)
{
    const int blk = blockIdx.x;
    const int dblk = blk & 15, c = (blk >> 4) & 7, b = blk >> 7;
    const int s = threadIdx.x & 15, dl = threadIdx.x >> 4;
    const int d = dblk*16 + dl;
    const float A = -__expf(Alog[d*DS + s]);
    const float Dv = Dp[d];
    const size_t r0 = (size_t)b*LL + c*CL;
    float h = hin[(((size_t)b*NC + c)*DM + d)*DS + s];
    for (int t = 0; t < CL; ++t) {
        size_t r = r0 + t;
        float dtv = dt[r*DM + d];   // read before same-wave store to same addr
        float xv  = xz[r*XZW + d];
        float Bv  = xz[r*XZW + 512 + s];
        float Cv  = xz[r*XZW + 528 + s];
        float dA  = __expf(dtv * A);
        h = fmaf(dA, h, dtv * xv * Bv);
        float p = h * Cv;
        p += __shfl_xor(p, 1);
        p += __shfl_xor(p, 2);
        p += __shfl_xor(p, 4);
        p += __shfl_xor(p, 8);
        if (s == 0) {
            float zv = xz[r*XZW + 256 + d];
            float sil = zv / (1.f + __expf(-zv));
            ssm[r*DM + d] = fmaf(p, sil, xv * Dv);
        }
    }
}

// ---------------- host ----------------
static inline void mgemm(hipStream_t st, const float* A, const unsigned short* W,
                         const float* bias, float* C, int M, int N, int Kp, int Kreal,
                         int lda, int ldc, int act, int accum) {
    dim3 g(M/128, (N+127)/128);
    mfma_gemm<<<g, 256, 0, st>>>(A, W, bias, C, N, Kp, Kreal, lda, ldc, act, accum);
}
static inline void gemm(hipStream_t st, const float* A, const float* W, const float* bias,
                        float* C, int M, int N, int K, int lda, int ldc, int act, int accum) {
    dim3 g(M/64, (N+63)/64);
    gemm_f32<<<g, 256, 0, st>>>(A, W, bias, C, N, K, lda, ldc, act, accum);
}

extern "C" void kernel_launch(void* const* d_in, const int* in_sizes, int n_in,
                              void* d_out, int out_size, void* d_ws, size_t ws_size,
                              hipStream_t stream) {
    (void)in_sizes; (void)n_in; (void)out_size; (void)ws_size;
    const float* obs      = (const float*)d_in[0];
    const int*   pa       = (const int*)d_in[1];
    const float* h0in[2]  = {(const float*)d_in[2], (const float*)d_in[3]};
    const float* kan_ln_g = (const float*)d_in[4];
    const float* kan_ln_b = (const float*)d_in[5];
    const float* kan_sp   = (const float*)d_in[6];
    const float* kan_sc   = (const float*)d_in[7];
    const float* kan_bias = (const float*)d_in[8];
    const float* kan_beta = (const float*)d_in[9];
    const float* fn_g     = (const float*)d_in[10];
    const float* fn_b     = (const float*)d_in[11];
    const float* gnn_W    = (const float*)d_in[12];
    const float* edge_w   = (const float*)d_in[13];
    const float* act_emb  = (const float*)d_in[14];
    const float* W_ip     = (const float*)d_in[15];
    const float* b_ip     = (const float*)d_in[16];
    const float* fl_g     = (const float*)d_in[37];
    const float* fl_b     = (const float*)d_in[38];
    const float* pW1      = (const float*)d_in[39];
    const float* pb1      = (const float*)d_in[40];
    const float* pW2      = (const float*)d_in[41];
    const float* pb2      = (const float*)d_in[42];
    const float* vW1      = (const float*)d_in[43];
    const float* vb1      = (const float*)d_in[44];
    const float* vW2      = (const float*)d_in[45];
    const float* vb2      = (const float*)d_in[46];

    // --- workspace arena (floats). Peak = 26,476,544 fl == proven footprint.
    const size_t SZ_BIG = (size_t)BLR * DM;           // 4,194,304
    float* ws = (float*)d_ws;
    float* X    = ws;                                 // residual
    float* R0   = X + SZ_BIG;                         // xn; kan-phase overlays:
    unsigned short* WIP16  = (unsigned short*)R0;                 // 256x320 bf16
    unsigned short* WAUG16 = WIP16 + (size_t)DM*CATP;             // 256x256 bf16
    float*          STATS  = (float*)(WAUG16 + (size_t)DM*KKANP); // 65536x2 f32
    float* XZBC = R0 + SZ_BIG;                        // BLR x 544 (x|z|B|C)
    float* R3   = XZBC + (size_t)BLR * XZW;           // dt -> ssm
    float* R4   = R3 + SZ_BIG;                        // cat BLRxCATD; layer overlays:
    const size_t CH = (size_t)BB * NC * DM * DS;      // 524,288
    float* Pbuf = R4;
    float* Sbuf = R4 + CH;
    float* HIN  = R4 + 2*CH;
    unsigned short* WIN16  = (unsigned short*)(R4 + 3*CH);        // 512x256 bf16
    unsigned short* WDT16  = WIN16 + 512*DM;                      // 256x256
    unsigned short* WOUT16 = WDT16 + DM*DM;                       // 256x256
    unsigned short* PW116  = WOUT16 + DM*DM;                      // 128x256
    unsigned short* VW116  = PW116 + 128*DM;                      // 64x256
    float* WBC = (float*)(VW116 + 64*DM);                         // 32x256 f32

    float* out        = (float*)d_out;
    float* out_logits = out;
    float* out_value  = out + (size_t)BLR * NACTN;
    float* out_h[2]   = {out + (size_t)BLR*NACTN + BLR,
                         out + (size_t)BLR*NACTN + BLR + (size_t)BB*DM*DS};

    // --- KAN phase (WIP16/WAUG16/STATS overlay R0, dead until layer 0) ---
    prep_waug16<<<(DM*KKANP+255)/256, 256, 0, stream>>>(kan_sp, kan_sc, WAUG16);
    prep_bf16<<<(DM*CATP+255)/256, 256, 0, stream>>>(W_ip, WIP16, DM, CATD, CATP);
    kan_stats<<<BLR*NF/4, 256, 0, stream>>>(obs, STATS);
    kan_fused<<<BLR*NF/128, 256, 0, stream>>>(
        obs, STATS, kan_ln_g, kan_ln_b, kan_beta, WAUG16, kan_bias, fn_g, fn_b, R4);
    graph_kernel<<<BLR, 64, 0, stream>>>(obs, gnn_W, edge_w, R4);
    gather_aemb<<<BLR*AEM/256, 256, 0, stream>>>(pa, act_emb, R4);

    // --- input projection: K=304 real, Kp=320 ---
    mgemm(stream, R4, WIP16, b_ip, X, BLR, DM, CATP, CATD, CATD, DM, 0, 0);

    // --- head weight preps (cat dead; R4 overlay) ---
    prep_bf16<<<(128*DM+255)/256, 256, 0, stream>>>(pW1, PW116, 128, DM, DM);
    prep_bf16<<<(64*DM+255)/256, 256, 0, stream>>>(vW1, VW116, 64, DM, DM);

    // --- two S6 layers ---
    for (int l = 0; l < 2; ++l) {
        const float* lng  = (const float*)d_in[17 + 10*l + 0];
        const float* lnb  = (const float*)d_in[17 + 10*l + 1];
        const float* Win  = (const float*)d_in[17 + 10*l + 2];
        const float* Wdt  = (const float*)d_in[17 + 10*l + 3];
        const float* bdt  = (const float*)d_in[17 + 10*l + 4];
        const float* Alog = (const float*)d_in[17 + 10*l + 5];
        const float* WBp  = (const float*)d_in[17 + 10*l + 6];
        const float* WCp  = (const float*)d_in[17 + 10*l + 7];
        const float* Dp   = (const float*)d_in[17 + 10*l + 8];
        const float* Wout = (const float*)d_in[17 + 10*l + 9];

        prep_bf16<<<(512*DM+255)/256, 256, 0, stream>>>(Win, WIN16, 512, DM, DM);
        prep_wbc<<<32, 256, 0, stream>>>(WBp, WCp, WBC);
        prep_bf16<<<(DM*DM+255)/256, 256, 0, stream>>>(Wdt, WDT16, DM, DM, DM);
        prep_bf16<<<(DM*DM+255)/256, 256, 0, stream>>>(Wout, WOUT16, DM, DM, DM);

        ln256<<<BLR/4, 256, 0, stream>>>(X, lng, lnb, R0);
        mgemm(stream, R0, WIN16, nullptr, XZBC, BLR, 512, DM, DM, DM, XZW, 0, 0);  // x|z
        gemm(stream, XZBC, WBC, nullptr, XZBC + 512, BLR, 32, DM, XZW, XZW, 0, 0); // B|C from x_in
        mgemm(stream, XZBC, WDT16, bdt, R3, BLR, DM, DM, DM, XZW, DM, 2, 0);       // dt from x_in
        s6_chunkA<<<BB*NC*16, 256, 0, stream>>>(R3, XZBC, Alog, Pbuf, Sbuf);
        s6_comb<<<BB*DM*DS/256, 256, 0, stream>>>(Pbuf, Sbuf, h0in[l], HIN, out_h[l]);
        s6_chunkC<<<BB*NC*16, 256, 0, stream>>>(R3, XZBC, Alog, HIN, Dp, R3);
        mgemm(stream, R3, WOUT16, nullptr, X, BLR, DM, DM, DM, DM, DM, 0, 1);
    }

    // --- heads (scratch in dead XZBC) ---
    float* H1 = XZBC;                     // BLR x 128
    float* H2 = XZBC + (size_t)BLR*128;   // BLR x 64
    ln256<<<BLR/4, 256, 0, stream>>>(X, fl_g, fl_b, R0);
    mgemm(stream, R0, PW116, pb1, H1, BLR, 128, DM, DM, DM, 128, 1, 0);
    gemm(stream, H1, pW2, pb2, out_logits, BLR, NACTN, 128, 128, NACTN, 0, 0);
    mgemm(stream, R0, VW116, vb1, H2, BLR, 64, DM, DM, DM, 64, 1, 0);
    gemm(stream, H2, vW2, vb2, out_value, BLR, 1, 64, 64, 1, 0, 0);
}

// Round 9
// 645.144 us; speedup vs baseline: 2.6119x; 1.1302x over previous
//
#include <hip/hip_runtime.h>
#include <math.h>

// ---------------- problem constants ----------------
#define BB   16
#define LL   1024
#define BLR  (BB*LL)        // 16384 rows
#define DM   256
#define DS   16
#define FD   115
#define NF   4
#define NACTN 19
#define GH   32
#define GKN  6
#define AEM  16
#define NP   22
#define CATD 304            // cat width (16-aligned, NOT padded)
#define CATP 320            // MFMA Kp for input proj
#define KKANP 256           // KAN K padded to x32
#define KREALK 230          // 115 inputs x {ln_x, sum_basis}
#define NC   8              // scan chunks
#define CL   (LL/NC)        // 128 steps per chunk
#define TT   16             // scan time-tile staged in LDS
#define LDK  40             // LDS row stride in bf16 elems
#define XZW  544            // x_in(256) | z(256) | B(16) | C(16)

// NOTE on the KAN: the reference einsum 'big,oid->bo' has MISMATCHED grid
// subscripts (g vs d) -> contraction over i only with (sum_g basis)*(sum_d Wsp).
// NOTE on B/C: Bt = x_in @ WB^T (NOT xn @ WB^T).

typedef __attribute__((ext_vector_type(8))) short bf16x8;
typedef __attribute__((ext_vector_type(4))) float f32x4;

__device__ inline unsigned short f2bf(float f) {
    unsigned int u = __float_as_uint(f);
    u += 0x7fff + ((u >> 16) & 1);
    return (unsigned short)(u >> 16);
}
__device__ inline unsigned int f2bf2(float lo, float hi) {
    return (unsigned int)f2bf(lo) | ((unsigned int)f2bf(hi) << 16);
}

// ============ MFMA GEMM: C[M,N] = act(A_f32[M,Kreal] @ W_bf16[N,Kp]^T + bias) (+C) ==
__global__ __launch_bounds__(256) void mfma_gemm(
    const float* __restrict__ A, const unsigned short* __restrict__ W,
    const float* __restrict__ bias, float* __restrict__ C,
    int N, int Kp, int Kreal, int lda, int ldc, int act, int accum)
{
    __shared__ __align__(16) unsigned short As[128*LDK];
    __shared__ __align__(16) unsigned short Ws[128*LDK];
    const int tid = threadIdx.x;
    const int bm = blockIdx.x * 128;
    const int bn = blockIdx.y * 128;
    const int wid = tid >> 6, lane = tid & 63;
    const int wr = wid >> 1, wc = wid & 1;
    const int g = lane >> 4, r16 = lane & 15;
    const int srow = tid >> 1;            // 0..127
    const int shalf = (tid & 1) * 16;     // k offset 0/16

    f32x4 acc[4][4] = {};
    for (int k0 = 0; k0 < Kp; k0 += 32) {
        uint4 alo = make_uint4(0u,0u,0u,0u), ahi = make_uint4(0u,0u,0u,0u);
        if (k0 + shalf < Kreal) {
            const float* ap = A + (size_t)(bm + srow) * lda + k0 + shalf;
            float4 a0 = *(const float4*)(ap);
            float4 a1 = *(const float4*)(ap + 4);
            float4 a2 = *(const float4*)(ap + 8);
            float4 a3 = *(const float4*)(ap + 12);
            alo = make_uint4(f2bf2(a0.x,a0.y), f2bf2(a0.z,a0.w),
                             f2bf2(a1.x,a1.y), f2bf2(a1.z,a1.w));
            ahi = make_uint4(f2bf2(a2.x,a2.y), f2bf2(a2.z,a2.w),
                             f2bf2(a3.x,a3.y), f2bf2(a3.z,a3.w));
        }
        unsigned short* ad = &As[srow*LDK + shalf];
        *(uint4*)(ad)     = alo;
        *(uint4*)(ad + 8) = ahi;
        int n = bn + srow;
        uint4 wv0 = make_uint4(0u,0u,0u,0u), wv1 = make_uint4(0u,0u,0u,0u);
        if (n < N) {
            const unsigned short* wp = W + (size_t)n * Kp + k0 + shalf;
            wv0 = ((const uint4*)wp)[0];
            wv1 = ((const uint4*)wp)[1];
        }
        unsigned short* wd = &Ws[srow*LDK + shalf];
        *(uint4*)(wd)     = wv0;
        *(uint4*)(wd + 8) = wv1;
        __syncthreads();

        bf16x8 af[4], bfr[4];
        #pragma unroll
        for (int mi = 0; mi < 4; ++mi)
            af[mi] = *reinterpret_cast<const bf16x8*>(&As[(wr*64 + mi*16 + r16)*LDK + g*8]);
        #pragma unroll
        for (int ni = 0; ni < 4; ++ni)
            bfr[ni] = *reinterpret_cast<const bf16x8*>(&Ws[(wc*64 + ni*16 + r16)*LDK + g*8]);
        #pragma unroll
        for (int mi = 0; mi < 4; ++mi)
            #pragma unroll
            for (int ni = 0; ni < 4; ++ni)
                acc[mi][ni] = __builtin_amdgcn_mfma_f32_16x16x32_bf16(
                    af[mi], bfr[ni], acc[mi][ni], 0, 0, 0);
        __syncthreads();
    }
    #pragma unroll
    for (int mi = 0; mi < 4; ++mi) {
        #pragma unroll
        for (int j = 0; j < 4; ++j) {
            int row = bm + wr*64 + mi*16 + g*4 + j;
            float* crow = C + (size_t)row * ldc;
            #pragma unroll
            for (int ni = 0; ni < 4; ++ni) {
                int col = bn + wc*64 + ni*16 + r16;
                if (col < N) {
                    float v = acc[mi][ni][j];
                    if (bias) v += bias[col];
                    if (act == 1) v = fmaxf(v, 0.f);
                    else if (act == 2) v = fmaxf(v, 0.f) + __logf(1.f + __expf(-fabsf(v)));
                    if (accum) v += crow[col];
                    crow[col] = v;
                }
            }
        }
    }
}

// ============ fused KAN: MFMA(gen(A), WAUG) + bias -> LN(256) -> relu -> frame-mean ==
__global__ __launch_bounds__(256) void kan_fused(
    const float* __restrict__ obs, const float* __restrict__ stats,
    const float* __restrict__ lng, const float* __restrict__ lnb,
    const float* __restrict__ betap, const unsigned short* __restrict__ W,
    const float* __restrict__ kbias, const float* __restrict__ fng,
    const float* __restrict__ fnb, float* __restrict__ cat)
{
    __shared__ __align__(16) unsigned short As[128*LDK];
    __shared__ __align__(16) unsigned short Ws[256*LDK];
    __shared__ float rsum[128][2];
    __shared__ float rsq[128][2];
    const float beta = fminf(fmaxf(betap[0], 0.5f), 6.0f);
    const int tid = threadIdx.x;
    const int bm = blockIdx.x * 128;
    const int wid = tid >> 6, lane = tid & 63;
    const int wr = wid >> 1, wc = wid & 1;
    const int g = lane >> 4, r16 = lane & 15;
    const int srow = tid >> 1;
    const int shalf = (tid & 1) * 16;
    const int r = bm + srow;
    const float m  = stats[2*r];
    const float rs = stats[2*r+1];
    const float* orow = obs + (size_t)r * FD;

    f32x4 acc[4][8] = {};
    for (int k0 = 0; k0 < KKANP; k0 += 32) {
        int i0 = (k0 + shalf) >> 1;
        unsigned int pk[8];
        #pragma unroll
        for (int q = 0; q < 8; ++q) {
            int i = i0 + q;
            float xv = 0.f, sb = 0.f;
            if (i < FD) {
                float x = (orow[i] - m) * rs * lng[i] + lnb[i];
                xv = x;
                #pragma unroll
                for (int g5 = 0; g5 < 5; ++g5) {
                    float dx = x - (-1.f + 0.5f * (float)g5);
                    sb += __expf(-dx*dx*beta);
                }
            }
            pk[q] = f2bf2(xv, sb);
        }
        unsigned short* ad = &As[srow*LDK + shalf];
        *(uint4*)(ad)     = make_uint4(pk[0], pk[1], pk[2], pk[3]);
        *(uint4*)(ad + 8) = make_uint4(pk[4], pk[5], pk[6], pk[7]);
        {
            const unsigned short* wp = W + (size_t)tid * KKANP + k0;
            uint4 w0 = ((const uint4*)wp)[0];
            uint4 w1 = ((const uint4*)wp)[1];
            uint4 w2 = ((const uint4*)wp)[2];
            uint4 w3 = ((const uint4*)wp)[3];
            unsigned short* wd = &Ws[tid*LDK];
            *(uint4*)(wd)      = w0;
            *(uint4*)(wd + 8)  = w1;
            *(uint4*)(wd + 16) = w2;
            *(uint4*)(wd + 24) = w3;
        }
        __syncthreads();
        bf16x8 af[4], bfr[8];
        #pragma unroll
        for (int mi = 0; mi < 4; ++mi)
            af[mi] = *reinterpret_cast<const bf16x8*>(&As[(wr*64 + mi*16 + r16)*LDK + g*8]);
        #pragma unroll
        for (int ni = 0; ni < 8; ++ni)
            bfr[ni] = *reinterpret_cast<const bf16x8*>(&Ws[(wc*128 + ni*16 + r16)*LDK + g*8]);
        #pragma unroll
        for (int mi = 0; mi < 4; ++mi)
            #pragma unroll
            for (int ni = 0; ni < 8; ++ni)
                acc[mi][ni] = __builtin_amdgcn_mfma_f32_16x16x32_bf16(
                    af[mi], bfr[ni], acc[mi][ni], 0, 0, 0);
        __syncthreads();
    }
    float bias8[8], g8[8], b8[8];
    #pragma unroll
    for (int ni = 0; ni < 8; ++ni) {
        int col = wc*128 + ni*16 + r16;
        bias8[ni] = kbias[col]; g8[ni] = fng[col]; b8[ni] = fnb[col];
    }
    #pragma unroll
    for (int mi = 0; mi < 4; ++mi) {
        #pragma unroll
        for (int j = 0; j < 4; ++j) {
            float s = 0.f, q = 0.f;
            #pragma unroll
            for (int ni = 0; ni < 8; ++ni) {
                float v = acc[mi][ni][j] + bias8[ni];
                s += v; q += v*v;
            }
            #pragma unroll
            for (int off = 1; off < 16; off <<= 1) {
                s += __shfl_xor(s, off);
                q += __shfl_xor(q, off);
            }
            if (r16 == 0) {
                int row = wr*64 + mi*16 + g*4 + j;
                rsum[row][wc] = s; rsq[row][wc] = q;
            }
        }
    }
    __syncthreads();
    #pragma unroll
    for (int mi = 0; mi < 4; ++mi) {
        int row0 = wr*64 + mi*16 + g*4;
        float o8[8] = {0.f,0.f,0.f,0.f,0.f,0.f,0.f,0.f};
        #pragma unroll
        for (int j = 0; j < 4; ++j) {
            int row = row0 + j;
            float sm = rsum[row][0] + rsum[row][1];
            float sq = rsq[row][0] + rsq[row][1];
            float mn = sm * (1.f/256.f);
            float var = fmaxf(sq * (1.f/256.f) - mn*mn, 0.f);
            float rstd = rsqrtf(var + 1e-5f);
            #pragma unroll
            for (int ni = 0; ni < 8; ++ni) {
                float v = acc[mi][ni][j] + bias8[ni];
                v = (v - mn) * rstd * g8[ni] + b8[ni];
                o8[ni] += fmaxf(v, 0.f);
            }
        }
        int rbl = (bm + row0) >> 2;
        float* crow = cat + (size_t)rbl * CATD;
        #pragma unroll
        for (int ni = 0; ni < 8; ++ni)
            crow[wc*128 + ni*16 + r16] = o8[ni] * 0.25f;
    }
}

// ---------------- generic f32 GEMM (tiny N: BC + heads) ----------------
__global__ __launch_bounds__(256) void gemm_f32(
    const float* __restrict__ A, const float* __restrict__ W,
    const float* __restrict__ bias, float* __restrict__ C,
    int N, int K, int lda, int ldc, int act, int accum)
{
    __shared__ float As[16][68];
    __shared__ float Ws[16][68];
    const int tid = threadIdx.x;
    const int bm = blockIdx.x * 64;
    const int bn = blockIdx.y * 64;
    const int ty = tid >> 4, tx = tid & 15;
    const int lr = tid >> 2;
    const int lk = (tid & 3) * 4;
    float acc[4][4] = {{0.f,0.f,0.f,0.f},{0.f,0.f,0.f,0.f},{0.f,0.f,0.f,0.f},{0.f,0.f,0.f,0.f}};

    for (int k0 = 0; k0 < K; k0 += 16) {
        float4 av = *reinterpret_cast<const float4*>(A + (size_t)(bm + lr) * lda + k0 + lk);
        As[lk+0][lr] = av.x; As[lk+1][lr] = av.y; As[lk+2][lr] = av.z; As[lk+3][lr] = av.w;
        float4 wv = make_float4(0.f, 0.f, 0.f, 0.f);
        if (bn + lr < N)
            wv = *reinterpret_cast<const float4*>(W + (size_t)(bn + lr) * K + k0 + lk);
        Ws[lk+0][lr] = wv.x; Ws[lk+1][lr] = wv.y; Ws[lk+2][lr] = wv.z; Ws[lk+3][lr] = wv.w;
        __syncthreads();
        #pragma unroll
        for (int kk = 0; kk < 16; ++kk) {
            float4 a4 = *reinterpret_cast<const float4*>(&As[kk][ty*4]);
            float4 b4 = *reinterpret_cast<const float4*>(&Ws[kk][tx*4]);
            float aa[4] = {a4.x, a4.y, a4.z, a4.w};
            float bb[4] = {b4.x, b4.y, b4.z, b4.w};
            #pragma unroll
            for (int i = 0; i < 4; ++i)
                #pragma unroll
                for (int j = 0; j < 4; ++j)
                    acc[i][j] = fmaf(aa[i], bb[j], acc[i][j]);
        }
        __syncthreads();
    }
    #pragma unroll
    for (int i = 0; i < 4; ++i) {
        int row = bm + ty*4 + i;
        #pragma unroll
        for (int j = 0; j < 4; ++j) {
            int col = bn + tx*4 + j;
            if (col < N) {
                float v = acc[i][j];
                if (bias) v += bias[col];
                if (act == 1) v = fmaxf(v, 0.f);
                size_t o = (size_t)row * ldc + col;
                if (accum) v += C[o];
                C[o] = v;
            }
        }
    }
}

// ---------------- prep kernels ----------------
__global__ void prep_bf16(const float* __restrict__ src, unsigned short* __restrict__ dst,
                          int N, int K, int Kp)
{
    int idx = blockIdx.x * 256 + threadIdx.x;
    if (idx >= N * Kp) return;
    int n = idx / Kp, k = idx - n * Kp;
    dst[idx] = (k < K) ? f2bf(src[(size_t)n * K + k]) : (unsigned short)0;
}

__global__ void prep_waug16(const float* __restrict__ sp, const float* __restrict__ sc,
                            unsigned short* __restrict__ Wg)
{
    int idx = blockIdx.x * 256 + threadIdx.x;
    if (idx >= DM * KKANP) return;
    int o = idx >> 8, k = idx & 255;
    float v = 0.f;
    if (k < KREALK) {
        int i = k >> 1;
        if (k & 1) {
            const float* s5 = sp + ((size_t)o*FD + i)*5;
            v = s5[0] + s5[1] + s5[2] + s5[3] + s5[4];
        } else v = sc[o*FD + i];
    }
    Wg[idx] = f2bf(v);
}

__global__ void prep_wbc(const float* __restrict__ WB, const float* __restrict__ WC,
                         float* __restrict__ Wg)
{
    int idx = blockIdx.x * 256 + threadIdx.x;   // 32*256
    if (idx >= 32 * DM) return;
    int n = idx >> 8, k = idx & 255;
    Wg[idx] = (n < 16) ? WB[n*DM + k] : WC[(n-16)*DM + k];
}

// ---------------- KAN per-row LN stats ----------------
__global__ __launch_bounds__(256) void kan_stats(const float* __restrict__ obs,
                                                 float* __restrict__ stats)
{
    int row = blockIdx.x * 4 + (threadIdx.x >> 6);
    int lane = threadIdx.x & 63;
    const float* o = obs + (size_t)row * FD;
    float v0 = o[lane];
    float v1 = (lane + 64 < FD) ? o[lane + 64] : 0.f;
    float s = v0 + v1;
    for (int off = 32; off; off >>= 1) s += __shfl_xor(s, off);
    float m = s * (1.f / FD);
    float e0 = v0 - m;
    float e1 = (lane + 64 < FD) ? (v1 - m) : 0.f;
    float ss = e0*e0 + e1*e1;
    for (int off = 32; off; off >>= 1) ss += __shfl_xor(ss, off);
    if (lane == 0) {
        stats[2*row]   = m;
        stats[2*row+1] = rsqrtf(ss * (1.f / FD) + 1e-5f);
    }
}

// ---------------- graph feature -> cat[256:288] ----------------
__global__ __launch_bounds__(64) void graph_kernel(const float* __restrict__ obs,
    const float* __restrict__ gW, const float* __restrict__ ewp,
    float* __restrict__ out)
{
    __shared__ float px[NP], py[NP];
    __shared__ float nodes[NP][8];
    __shared__ float gxs[NP][GH];
    __shared__ unsigned int msk[NP];
    __shared__ float rden[NP];
    __shared__ float wgt[NP];
    const int row = blockIdx.x;
    const int lane = threadIdx.x;
    const float* fc = obs + ((size_t)row * NF + 3) * FD;
    const float* fp = obs + ((size_t)row * NF + 2) * FD;
    const float ew = ewp[0];

    if (lane < NP) {
        int i = lane;
        float p0, p1, q0, q1;
        if (i < 11) { p0 = fc[3+2*i];  p1 = fc[4+2*i];  q0 = fp[3+2*i];  q1 = fp[4+2*i]; }
        else { int ii = i-11; p0 = fc[25+2*ii]; p1 = fc[26+2*ii]; q0 = fp[25+2*ii]; q1 = fp[26+2*ii]; }
        px[i] = p0; py[i] = p1;
        float bx = fc[0], by = fc[1];
        float bd = sqrtf((p0-bx)*(p0-bx) + (p1-by)*(p1-by));
        nodes[i][0] = p0; nodes[i][1] = p1;
        nodes[i][2] = p0 - q0; nodes[i][3] = p1 - q1;
        nodes[i][4] = (i < 11) ? 0.f : 1.f;
        nodes[i][5] = __expf(-2.f * bd);
    }
    __syncthreads();
    if (lane < NP) {
        int base = (lane < 11) ? 0 : 11;
        float cx = 0.f, cy = 0.f;
        for (int j = 0; j < 11; ++j) { cx += px[base+j]; cy += py[base+j]; }
        cx *= (1.f/11.f); cy *= (1.f/11.f);
        nodes[lane][6] = px[lane] - cx;
        nodes[lane][7] = py[lane] - cy;
        unsigned sel = 0;
        for (int k = 0; k < GKN; ++k) {
            float best = 1e30f; int bj = 0;
            for (int j = 0; j < NP; ++j) {
                if (j == lane || ((sel >> j) & 1u)) continue;
                float dx = px[lane]-px[j], dy = py[lane]-py[j];
                float dd = sqrtf(dx*dx + dy*dy);
                if (dd < best) { best = dd; bj = j; }
            }
            sel |= (1u << bj);
        }
        unsigned full = sel | (1u << lane);
        msk[lane] = full;
        rden[lane] = 1.f / fmaxf((float)__popc(full), 1.f);
    }
    __syncthreads();
    for (int idx = lane; idx < NP*GH; idx += 64) {
        int i = idx >> 5, h = idx & 31;
        float s = 0.f;
        #pragma unroll
        for (int f = 0; f < 8; ++f) s += nodes[i][f] * gW[h*8 + f];
        gxs[i][h] = s;
    }
    __syncthreads();
    if (lane < NP) {
        float s = 0.f;
        for (int i = 0; i < NP; ++i) if ((msk[i] >> lane) & 1u) s += rden[i];
        wgt[lane] = (1.f - ew) + ew * s;
    }
    __syncthreads();
    if (lane < GH) {
        float s = 0.f;
        for (int j = 0; j < NP; ++j) s += wgt[j] * gxs[j][lane];
        out[(size_t)row * CATD + DM + lane] = s * (1.f/22.f);
    }
}

// ---------------- action embedding gather -> cat[288:304] ----------------
__global__ void gather_aemb(const int* __restrict__ pa, const float* __restrict__ emb,
                            float* __restrict__ out)
{
    int idx = blockIdx.x * 256 + threadIdx.x;
    int row = idx >> 4, e = idx & 15;
    out[(size_t)row * CATD + DM + GH + e] = emb[pa[row]*AEM + e];
}

// ---------------- LN over 256 cols ----------------
__global__ __launch_bounds__(256) void ln256(const float* __restrict__ X,
    const float* __restrict__ g, const float* __restrict__ b, float* __restrict__ Y)
{
    int row = blockIdx.x * 4 + (threadIdx.x >> 6);
    int lane = threadIdx.x & 63;
    const float* x = X + (size_t)row * DM;
    float4 v = reinterpret_cast<const float4*>(x)[lane];
    float s = v.x + v.y + v.z + v.w;
    for (int off = 32; off; off >>= 1) s += __shfl_xor(s, off);
    float m = s * (1.f / DM);
    float d0 = v.x-m, d1 = v.y-m, d2 = v.z-m, d3 = v.w-m;
    float ss = d0*d0 + d1*d1 + d2*d2 + d3*d3;
    for (int off = 32; off; off >>= 1) ss += __shfl_xor(ss, off);
    float rstd = rsqrtf(ss * (1.f / DM) + 1e-5f);
    int c = lane * 4;
    float4 o4 = make_float4(d0*rstd*g[c+0] + b[c+0],
                            d1*rstd*g[c+1] + b[c+1],
                            d2*rstd*g[c+2] + b[c+2],
                            d3*rstd*g[c+3] + b[c+3]);
    reinterpret_cast<float4*>(Y + (size_t)row * DM)[lane] = o4;
}

// ======== S6 chunked parallel scan, LDS-staged 16-step tiles ========
// Block = (b, chunk, dblk): 16 d x 16 s. Per tile: cooperative float4 loads.
__global__ __launch_bounds__(256) void s6_chunkA(
    const float* __restrict__ dt, const float* __restrict__ xz,
    const float* __restrict__ Alog, float* __restrict__ P, float* __restrict__ S)
{
    __shared__ float sdt[TT][16], sx[TT][16], sB[TT][16];
    const int blk = blockIdx.x;
    const int dblk = blk & 15, c = (blk >> 4) & 7, b = blk >> 7;
    const int s = threadIdx.x & 15, dl = threadIdx.x >> 4;
    const int d0 = dblk*16, d = d0 + dl;
    const float A = -__expf(Alog[d*DS + s]);
    const size_t r0 = (size_t)b*LL + c*CL;
    const int u = threadIdx.x & 63, grp = threadIdx.x >> 6;
    const int lt = u >> 2, lc = (u & 3) * 4;
    float Pv = 1.f, Sv = 0.f;
    for (int t0 = 0; t0 < CL; t0 += TT) {
        size_t rb = r0 + t0 + lt;
        if (grp == 0)      *(float4*)&sdt[lt][lc] = *(const float4*)(dt + rb*DM  + d0 + lc);
        else if (grp == 1) *(float4*)&sx[lt][lc]  = *(const float4*)(xz + rb*XZW + d0 + lc);
        else if (grp == 2) *(float4*)&sB[lt][lc]  = *(const float4*)(xz + rb*XZW + 512 + lc);
        __syncthreads();
        #pragma unroll
        for (int tt = 0; tt < TT; ++tt) {
            float dtv = sdt[tt][dl];
            float dA  = __expf(dtv * A);
            Pv *= dA;
            Sv = fmaf(dA, Sv, dtv * sx[tt][dl] * sB[tt][s]);
        }
        __syncthreads();
    }
    size_t o = (((size_t)b*NC + c)*DM + d)*DS + s;
    P[o] = Pv; S[o] = Sv;
}

__global__ __launch_bounds__(256) void s6_comb(
    const float* __restrict__ P, const float* __restrict__ S,
    const float* __restrict__ h0, float* __restrict__ hin, float* __restrict__ hout)
{
    int idx = blockIdx.x * 256 + threadIdx.x;
    int b = idx >> 12, ds = idx & 4095;
    float h = h0[idx];
    #pragma unroll
    for (int c = 0; c < NC; ++c) {
        size_t o = (((size_t)b*NC + c) << 12) + ds;
        hin[o] = h;
        h = fmaf(P[o], h, S[o]);
    }
    hout[idx] = h;
}

// ssm may alias dt: each (r,d) is loaded to LDS at tile start, stored later in the
// same tile by the SAME block; blocks own disjoint (r,d) regions -> no hazard.
__global__ __launch_bounds__(256) void s6_chunkC(
    const float* __restrict__ dt, const float* __restrict__ xz,
    const float* __restrict__ Alog, const float* __restrict__ hin,
    const float* __restrict__ Dp, float* __restrict__ ssm)
{
    __shared__ float sdt[TT][16], sx[TT][16], sz[TT][16], sB[TT][16], sC[TT][16];
    const int blk = blockIdx.x;
    const int dblk = blk & 15, c = (blk >> 4) & 7, b = blk >> 7;
    const int s = threadIdx.x & 15, dl = threadIdx.x >> 4;
    const int d0 = dblk*16, d = d0 + dl;
    const float A = -__expf(Alog[d*DS + s]);
    const float Dv = Dp[d];
    const size_t r0 = (size_t)b*LL + c*CL;
    const int u = threadIdx.x & 63, grp = threadIdx.x >> 6;
    const int lt = u >> 2, lc = (u & 3) * 4;
    float h = hin[(((size_t)b*NC + c)*DM + d)*DS + s];
    for (int t0 = 0; t0 < CL; t0 += TT) {
        size_t rb = r0 + t0 + lt;
        if (grp == 0)      *(float4*)&sdt[lt][lc] = *(const float4*)(dt + rb*DM  + d0 + lc);
        else if (grp == 1) *(float4*)&sx[lt][lc]  = *(const float4*)(xz + rb*XZW + d0 + lc);
        else if (grp == 2) *(float4*)&sz[lt][lc]  = *(const float4*)(xz + rb*XZW + 256 + d0 + lc);
        else {
            *(float4*)&sB[lt][lc] = *(const float4*)(xz + rb*XZW + 512 + lc);
            *(float4*)&sC[lt][lc] = *(const float4*)(xz + rb*XZW + 528 + lc);
        }
        __syncthreads();
        #pragma unroll
        for (int tt = 0; tt < TT; ++tt) {
            float dtv = sdt[tt][dl];
            float xv  = sx[tt][dl];
            float dA  = __expf(dtv * A);
            h = fmaf(dA, h, dtv * xv * sB[tt][s]);
            float p = h * sC[tt][s];
            p += __shfl_xor(p, 1);
            p += __shfl_xor(p, 2);
            p += __shfl_xor(p, 4);
            p += __shfl_xor(p, 8);
            if (s == 0) {
                float zv = sz[tt][dl];
                float sil = zv / (1.f + __expf(-zv));
                ssm[(r0 + t0 + tt)*DM + d] = fmaf(p, sil, xv * Dv);
            }
        }
        __syncthreads();
    }
}

// ---------------- host ----------------
static inline void mgemm(hipStream_t st, const float* A, const unsigned short* W,
                         const float* bias, float* C, int M, int N, int Kp, int Kreal,
                         int lda, int ldc, int act, int accum) {
    dim3 g(M/128, (N+127)/128);
    mfma_gemm<<<g, 256, 0, st>>>(A, W, bias, C, N, Kp, Kreal, lda, ldc, act, accum);
}
static inline void gemm(hipStream_t st, const float* A, const float* W, const float* bias,
                        float* C, int M, int N, int K, int lda, int ldc, int act, int accum) {
    dim3 g(M/64, (N+63)/64);
    gemm_f32<<<g, 256, 0, st>>>(A, W, bias, C, N, K, lda, ldc, act, accum);
}

extern "C" void kernel_launch(void* const* d_in, const int* in_sizes, int n_in,
                              void* d_out, int out_size, void* d_ws, size_t ws_size,
                              hipStream_t stream) {
    (void)in_sizes; (void)n_in; (void)out_size; (void)ws_size;
    const float* obs      = (const float*)d_in[0];
    const int*   pa       = (const int*)d_in[1];
    const float* h0in[2]  = {(const float*)d_in[2], (const float*)d_in[3]};
    const float* kan_ln_g = (const float*)d_in[4];
    const float* kan_ln_b = (const float*)d_in[5];
    const float* kan_sp   = (const float*)d_in[6];
    const float* kan_sc   = (const float*)d_in[7];
    const float* kan_bias = (const float*)d_in[8];
    const float* kan_beta = (const float*)d_in[9];
    const float* fn_g     = (const float*)d_in[10];
    const float* fn_b     = (const float*)d_in[11];
    const float* gnn_W    = (const float*)d_in[12];
    const float* edge_w   = (const float*)d_in[13];
    const float* act_emb  = (const float*)d_in[14];
    const float* W_ip     = (const float*)d_in[15];
    const float* b_ip     = (const float*)d_in[16];
    const float* fl_g     = (const float*)d_in[37];
    const float* fl_b     = (const float*)d_in[38];
    const float* pW1      = (const float*)d_in[39];
    const float* pb1      = (const float*)d_in[40];
    const float* pW2      = (const float*)d_in[41];
    const float* pb2      = (const float*)d_in[42];
    const float* vW1      = (const float*)d_in[43];
    const float* vb1      = (const float*)d_in[44];
    const float* vW2      = (const float*)d_in[45];
    const float* vb2      = (const float*)d_in[46];

    // --- workspace arena (floats). Peak = 26,476,544 fl == proven footprint.
    const size_t SZ_BIG = (size_t)BLR * DM;           // 4,194,304
    float* ws = (float*)d_ws;
    float* X    = ws;                                 // residual
    float* R0   = X + SZ_BIG;                         // xn; kan-phase overlays:
    unsigned short* WIP16  = (unsigned short*)R0;                 // 256x320 bf16
    unsigned short* WAUG16 = WIP16 + (size_t)DM*CATP;             // 256x256 bf16
    float*          STATS  = (float*)(WAUG16 + (size_t)DM*KKANP); // 65536x2 f32
    float* XZBC = R0 + SZ_BIG;                        // BLR x 544 (x|z|B|C)
    float* R3   = XZBC + (size_t)BLR * XZW;           // dt -> ssm
    float* R4   = R3 + SZ_BIG;                        // cat BLRxCATD; layer overlays:
    const size_t CH = (size_t)BB * NC * DM * DS;      // 524,288
    float* Pbuf = R4;
    float* Sbuf = R4 + CH;
    float* HIN  = R4 + 2*CH;
    unsigned short* WIN16  = (unsigned short*)(R4 + 3*CH);        // 512x256 bf16
    unsigned short* WDT16  = WIN16 + 512*DM;                      // 256x256
    unsigned short* WOUT16 = WDT16 + DM*DM;                       // 256x256
    unsigned short* PW116  = WOUT16 + DM*DM;                      // 128x256
    unsigned short* VW116  = PW116 + 128*DM;                      // 64x256
    float* WBC = (float*)(VW116 + 64*DM);                         // 32x256 f32

    float* out        = (float*)d_out;
    float* out_logits = out;
    float* out_value  = out + (size_t)BLR * NACTN;
    float* out_h[2]   = {out + (size_t)BLR*NACTN + BLR,
                         out + (size_t)BLR*NACTN + BLR + (size_t)BB*DM*DS};

    // --- KAN phase (WIP16/WAUG16/STATS overlay R0, dead until layer 0) ---
    prep_waug16<<<(DM*KKANP+255)/256, 256, 0, stream>>>(kan_sp, kan_sc, WAUG16);
    prep_bf16<<<(DM*CATP+255)/256, 256, 0, stream>>>(W_ip, WIP16, DM, CATD, CATP);
    kan_stats<<<BLR*NF/4, 256, 0, stream>>>(obs, STATS);
    kan_fused<<<BLR*NF/128, 256, 0, stream>>>(
        obs, STATS, kan_ln_g, kan_ln_b, kan_beta, WAUG16, kan_bias, fn_g, fn_b, R4);
    graph_kernel<<<BLR, 64, 0, stream>>>(obs, gnn_W, edge_w, R4);
    gather_aemb<<<BLR*AEM/256, 256, 0, stream>>>(pa, act_emb, R4);

    // --- input projection: K=304 real, Kp=320 ---
    mgemm(stream, R4, WIP16, b_ip, X, BLR, DM, CATP, CATD, CATD, DM, 0, 0);

    // --- head weight preps (cat dead; R4 overlay) ---
    prep_bf16<<<(128*DM+255)/256, 256, 0, stream>>>(pW1, PW116, 128, DM, DM);
    prep_bf16<<<(64*DM+255)/256, 256, 0, stream>>>(vW1, VW116, 64, DM, DM);

    // --- two S6 layers ---
    for (int l = 0; l < 2; ++l) {
        const float* lng  = (const float*)d_in[17 + 10*l + 0];
        const float* lnb  = (const float*)d_in[17 + 10*l + 1];
        const float* Win  = (const float*)d_in[17 + 10*l + 2];
        const float* Wdt  = (const float*)d_in[17 + 10*l + 3];
        const float* bdt  = (const float*)d_in[17 + 10*l + 4];
        const float* Alog = (const float*)d_in[17 + 10*l + 5];
        const float* WBp  = (const float*)d_in[17 + 10*l + 6];
        const float* WCp  = (const float*)d_in[17 + 10*l + 7];
        const float* Dp   = (const float*)d_in[17 + 10*l + 8];
        const float* Wout = (const float*)d_in[17 + 10*l + 9];

        prep_bf16<<<(512*DM+255)/256, 256, 0, stream>>>(Win, WIN16, 512, DM, DM);
        prep_wbc<<<32, 256, 0, stream>>>(WBp, WCp, WBC);
        prep_bf16<<<(DM*DM+255)/256, 256, 0, stream>>>(Wdt, WDT16, DM, DM, DM);
        prep_bf16<<<(DM*DM+255)/256, 256, 0, stream>>>(Wout, WOUT16, DM, DM, DM);

        ln256<<<BLR/4, 256, 0, stream>>>(X, lng, lnb, R0);
        mgemm(stream, R0, WIN16, nullptr, XZBC, BLR, 512, DM, DM, DM, XZW, 0, 0);  // x|z
        gemm(stream, XZBC, WBC, nullptr, XZBC + 512, BLR, 32, DM, XZW, XZW, 0, 0); // B|C from x_in
        mgemm(stream, XZBC, WDT16, bdt, R3, BLR, DM, DM, DM, XZW, DM, 2, 0);       // dt from x_in
        s6_chunkA<<<BB*NC*16, 256, 0, stream>>>(R3, XZBC, Alog, Pbuf, Sbuf);
        s6_comb<<<BB*DM*DS/256, 256, 0, stream>>>(Pbuf, Sbuf, h0in[l], HIN, out_h[l]);
        s6_chunkC<<<BB*NC*16, 256, 0, stream>>>(R3, XZBC, Alog, HIN, Dp, R3);
        mgemm(stream, R3, WOUT16, nullptr, X, BLR, DM, DM, DM, DM, DM, 0, 1);
    }

    // --- heads (scratch in dead XZBC) ---
    float* H1 = XZBC;                     // BLR x 128
    float* H2 = XZBC + (size_t)BLR*128;   // BLR x 64
    ln256<<<BLR/4, 256, 0, stream>>>(X, fl_g, fl_b, R0);
    mgemm(stream, R0, PW116, pb1, H1, BLR, 128, DM, DM, DM, 128, 1, 0);
    gemm(stream, H1, pW2, pb2, out_logits, BLR, NACTN, 128, 128, NACTN, 0, 0);
    mgemm(stream, R0, VW116, vb1, H2, BLR, 64, DM, DM, DM, 64, 1, 0);
    gemm(stream, H2, vW2, vb2, out_value, BLR, 1, 64, 64, 1, 0, 0);
}